// Round 7
// baseline (1660.447 us; speedup 1.0000x reference)
//
#include <hip/hip_runtime.h>
#include <hip/hip_bf16.h>
#include <hip/hip_cooperative_groups.h>

namespace cg = cooperative_groups;

#define DEV __device__ __forceinline__

typedef unsigned short u16;
typedef short bf16x8_t __attribute__((ext_vector_type(8)));
typedef float f32x4_t __attribute__((ext_vector_type(4)));

// Model dims: B=256 H=1024 F=512 P=66 T_IN=10 T_OUT=25, gates 4H=4096
// enc K = F+H = 1536 ; dec: gemm1 hd@Wx (K=1024) + gemm2 atth@Whh (K=1024, acc)
constexpr int NBLK = 256;
constexpr int NTHR = 512;
constexpr int NT_ALL = NBLK * NTHR;
constexpr size_t HSTRIDE = 256 * 1024;
// LDS: A slots 4 x 8KB @ [0..32K); all overlays (ep/attention/finalproj) @ 32K+
constexpr int SMEM_BYTES = 86016;

struct Params {
  const float *x, *z, *resid, *tf_w, *tf_b;
  const float *e_wih, *e_whh, *e_bih, *e_bhh;
  const float *p_wih, *p_whh, *p_bih, *p_bhh;
  const float *d_wih, *d_whh, *d_bih, *d_bhh;
  const float *lin_w, *lin_b, *tp_w, *tp_b;
  u16 *Wenc, *Wencp, *Wdec, *wihP, *linT, *tpw;
  float *bias_e, *bias_ep, *bias_d, *bias_part;
  u16 *xf, *zf;
  u16 *he, *hp;            // 11 step-buffers each
  u16 *hs;                 // 25 decoder h buffers
  u16 *atth;               // 25 step-buffers
  float *c_pub;            // 2 ping-pong f32 [256][1024]
  unsigned *bar;           // ctr[i*16]: 0..7 full-grid, 8..39 lane-scoped (8/lane)
  float *out;
};

DEV float b2f(u16 v) { unsigned u = ((unsigned)v) << 16; float f; __builtin_memcpy(&f, &u, 4); return f; }
DEV u16 f2b(float f) {
  unsigned u; __builtin_memcpy(&u, &f, 4);
  unsigned r = u + 0x7fffu + ((u >> 16) & 1u);   // RNE
  return (u16)(r >> 16);
}
DEV unsigned pk2(float a, float b) { return (unsigned)f2b(a) | ((unsigned)f2b(b) << 16); }
DEV uint4 cvt8(const float* s) {
  float4 a = *(const float4*)s;
  float4 b = *(const float4*)(s + 4);
  uint4 r;
  r.x = pk2(a.x, a.y); r.y = pk2(a.z, a.w);
  r.z = pk2(b.x, b.y); r.w = pk2(b.z, b.w);
  return r;
}
DEV float sigm(float x) { return 1.0f / (1.0f + __expf(-x)); }
DEV f32x4_t fzero4() { f32x4_t v = {0.f, 0.f, 0.f, 0.f}; return v; }

DEV void gll16(const void* g, void* l) {
  __builtin_amdgcn_global_load_lds(
      (const __attribute__((address_space(1))) void*)g,
      (__attribute__((address_space(3))) void*)l, 16, 0, 0);
}

template <typename T> DEV void st_wt(T* p, T v) {
  __hip_atomic_store(p, v, __ATOMIC_RELAXED, __HIP_MEMORY_SCOPE_AGENT);
}
template <typename T> DEV T ld_byp(const T* p) {
  return __hip_atomic_load(p, __ATOMIC_RELAXED, __HIP_MEMORY_SCOPE_AGENT);
}

// ---- fence-free barriers: monotonic counters, no cache flush ----
DEV void fullbar(unsigned* ctrs, int bid, unsigned tgt, int tid) {
  asm volatile("s_waitcnt vmcnt(0)" ::: "memory");
  __syncthreads();
  if (tid == 0) atomicAdd(&ctrs[(bid & 7) * 16], 1u);
  if (tid < 8) { while (ld_byp(&ctrs[tid * 16]) < tgt) __builtin_amdgcn_s_sleep(2); }
  __syncthreads();
}
// lane-scoped (64 blocks), 8-way split counters to avoid atomic serialization
DEV void lanebar8(unsigned* ctrs, int lane, int j, unsigned tgt, int tid) {
  asm volatile("s_waitcnt vmcnt(0)" ::: "memory");
  __syncthreads();
  if (tid == 0) atomicAdd(&ctrs[(8 + lane * 8 + (j & 7)) * 16], 1u);
  if (tid < 8) { while (ld_byp(&ctrs[(8 + lane * 8 + tid) * 16]) < tgt) __builtin_amdgcn_s_sleep(1); }
  __syncthreads();
}

// ------------- 64x64-tile bf16 GEMM: A via LDS, B direct-to-register -------
// Waves 4m x 2n of 16x32, acc[2] (accumulates into caller's acc).
// A: 4 rotating 8KB LDS slots @ sm[0..32K), staged via global_load_lds with
// source-side XOR swizzle (16B unit ^= row&7) + same XOR on ds_read_b128.
// B: double-buffered in LOCAL registers (sets E/O), loaded as plain global
// reads -- compiler tracks their RAW deps; our counted vmcnt only guarantees
// the gll16->LDS data. Schedule per body:
//   [wait vmcnt(W); sched_barrier; s_barrier; sched_barrier;
//    ds_read A(ks); 4x MFMA; issue A(ks+2)+B(ks+2)]
// W=5 steady (leaves the 5 ops of the next k-step in flight), W=0 at the end.
// Robust to extra compiler VMEM ops: drains are oldest-first, and every
// window between asm barriers holds >= 5 ops, so vmcnt(5) always fully
// drains the window issued two bodies ago.
struct Bpre { bf16x8_t e00, e01, e10, e11, o00, o01, o10, o11; };

DEV void gemmT(const u16* __restrict__ xa, int ldx, int xcols,
               const u16* __restrict__ ha, int ldh,
               const u16* __restrict__ w, int ldw, int K,
               int m0, int n0, int tid, char* sm, f32x4_t acc[2]) {
  Bpre B;                                   // function-local: no state crosses
  const int NK = K >> 6;
  const int row = tid >> 3, usw8 = ((tid & 7) ^ (row & 7)) * 8, wv = tid >> 6;
  char* dst = sm + (wv << 10);
  const u16* aX = xa + (size_t)(m0 + row) * ldx + usw8;
  const u16* aH = ha + (size_t)(m0 + row) * ldh + usw8 - xcols;
  const int wc = (tid >> 6) & 1, l15 = tid & 15, lhi = (tid & 63) >> 4;
  const u16* pb0 = w + (size_t)(n0 + wc * 32 + l15) * ldw + lhi * 8;
  const u16* pb1 = pb0 + (size_t)16 * ldw;
  const int rA = (tid >> 7) * 16 + l15;     // wr = wv>>1
  const int aoff0 = rA * 128 + ((lhi ^ (rA & 7)) << 4);
  const int aoff1 = rA * 128 + (((lhi + 4) ^ (rA & 7)) << 4);

  auto sA = [&](int ks) {
    const int k0 = ks << 6;
    const u16* g = (k0 < xcols) ? (aX + k0) : (aH + k0);
    gll16(g, dst + ((ks & 3) << 13));
  };
  auto ldE = [&](int ks) {
    const int k0 = ks << 6;
    B.e00 = *(const bf16x8_t*)(pb0 + k0);
    B.e01 = *(const bf16x8_t*)(pb0 + k0 + 32);
    B.e10 = *(const bf16x8_t*)(pb1 + k0);
    B.e11 = *(const bf16x8_t*)(pb1 + k0 + 32);
  };
  auto ldO = [&](int ks) {
    const int k0 = ks << 6;
    B.o00 = *(const bf16x8_t*)(pb0 + k0);
    B.o01 = *(const bf16x8_t*)(pb0 + k0 + 32);
    B.o10 = *(const bf16x8_t*)(pb1 + k0);
    B.o11 = *(const bf16x8_t*)(pb1 + k0 + 32);
  };

  sA(0); ldE(0); sA(1); ldO(1);             // entry prefetch: 10 VMEM ops

  auto body = [&](int ks, bool useE, int wN, bool issue) {
    if (wN == 5) asm volatile("s_waitcnt vmcnt(5)" ::: "memory");
    else         asm volatile("s_waitcnt vmcnt(0)" ::: "memory");
    __builtin_amdgcn_sched_barrier(0);
    __builtin_amdgcn_s_barrier();
    __builtin_amdgcn_sched_barrier(0);
    const char* Asl = sm + ((ks & 3) << 13);
    bf16x8_t a0 = *(const bf16x8_t*)(Asl + aoff0);
    bf16x8_t a1 = *(const bf16x8_t*)(Asl + aoff1);
    if (useE) {
      acc[0] = __builtin_amdgcn_mfma_f32_16x16x32_bf16(a0, B.e00, acc[0], 0, 0, 0);
      acc[0] = __builtin_amdgcn_mfma_f32_16x16x32_bf16(a1, B.e01, acc[0], 0, 0, 0);
      acc[1] = __builtin_amdgcn_mfma_f32_16x16x32_bf16(a0, B.e10, acc[1], 0, 0, 0);
      acc[1] = __builtin_amdgcn_mfma_f32_16x16x32_bf16(a1, B.e11, acc[1], 0, 0, 0);
    } else {
      acc[0] = __builtin_amdgcn_mfma_f32_16x16x32_bf16(a0, B.o00, acc[0], 0, 0, 0);
      acc[0] = __builtin_amdgcn_mfma_f32_16x16x32_bf16(a1, B.o01, acc[0], 0, 0, 0);
      acc[1] = __builtin_amdgcn_mfma_f32_16x16x32_bf16(a0, B.o10, acc[1], 0, 0, 0);
      acc[1] = __builtin_amdgcn_mfma_f32_16x16x32_bf16(a1, B.o11, acc[1], 0, 0, 0);
    }
    if (issue) { sA(ks + 2); if (useE) ldE(ks + 2); else ldO(ks + 2); }
  };

  body(0, true, 5, true);
  body(1, false, 5, true);
#pragma unroll 1
  for (int ks = 2; ks < NK - 2; ks += 2) {
    body(ks, true, 5, true);
    body(ks + 1, false, 5, true);
  }
  body(NK - 2, true, 5, false);
  body(NK - 1, false, 0, false);
}

// ----------------- LSTM pointwise epilogue, c in registers -----------------
// Overlay [64][68] f32 @ sm+32768 (never aliases A slots).
DEV void lstm_ep(const f32x4_t acc[2], int tid, char* sm,
                 const float* __restrict__ bias, float cc[2],
                 u16* __restrict__ hw, float* __restrict__ cpub,
                 int m0, int n0) {
  float* gl = (float*)(sm + 32768);
  const int l15 = tid & 15, lhi = (tid & 63) >> 4;
  const int wv = tid >> 6, wr = wv >> 1, wc = wv & 1;
#pragma unroll
  for (int jf = 0; jf < 2; ++jf)
#pragma unroll
    for (int qq = 0; qq < 4; ++qq)
      gl[(wr * 16 + lhi * 4 + qq) * 68 + wc * 32 + jf * 16 + l15] = acc[jf][qq];
  __syncthreads();
#pragma unroll
  for (int it = 0; it < 2; ++it) {
    int idx = it * 512 + tid;           // 1024 items: 64 rows x 16 j
    int r = idx >> 4, jj = idx & 15;
    f32x4_t g4 = *(const f32x4_t*)(gl + r * 68 + jj * 4);
    f32x4_t b4 = *(const f32x4_t*)(bias + n0 + jj * 4);
    float ig = sigm(g4[0] + b4[0]);
    float fg = sigm(g4[1] + b4[1]);
    float g_ = tanhf(g4[2] + b4[2]);
    float og = sigm(g4[3] + b4[3]);
    float cn = fg * cc[it] + ig * g_;
    cc[it] = cn;
    float hn = og * tanhf(cn);
    size_t off = (size_t)(m0 + r) * 1024 + (n0 >> 2) + jj;
    st_wt(&hw[off], f2b(hn));
    if (cpub) st_wt(&cpub[off], cn);
  }
  __syncthreads();
}

DEV void wx_store(const f32x4_t acc[2], int tid, u16* __restrict__ Wdec,
                  int m0, int n0) {
  const int l15 = tid & 15, lhi = (tid & 63) >> 4;
  const int wv = tid >> 6, wr = wv >> 1, wc = wv & 1;
#pragma unroll
  for (int jf = 0; jf < 2; ++jf)
#pragma unroll
    for (int qq = 0; qq < 4; ++qq) {
      int r = m0 + wr * 16 + lhi * 4 + qq;
      int c = n0 + wc * 32 + jf * 16 + l15;
      st_wt(&Wdec[(size_t)r * 2048 + c], f2b(acc[jf][qq]));
    }
}

// ------------------- phase 0: ToFeature (block-cooperative) ----------------
DEV void phase0_tf(const Params& p, int bid, int tid, char* sm) {
  float* xs = (float*)sm;            // [10][66]
  float* zs = (float*)(sm + 2688);
  for (int g = tid; g < 660; g += NTHR) {
    int t = g / 66, qd = g - t * 66;
    xs[g] = p.x[((size_t)bid * 10 + t) * 66 + qd];
    zs[g] = p.z[((size_t)bid * 10 + t) * 66 + qd];
  }
  __syncthreads();
  const int n = tid;
  float accx[10], accz[10];
  float bn = p.tf_b[n];
#pragma unroll
  for (int t = 0; t < 10; ++t) { accx[t] = bn; accz[t] = bn; }
  const float* wrow = p.tf_w + (size_t)n * 66;
  for (int k = 0; k < 66; ++k) {
    float wk = wrow[k];
#pragma unroll
    for (int t = 0; t < 10; ++t) {
      accx[t] = fmaf(wk, xs[t * 66 + k], accx[t]);
      accz[t] = fmaf(wk, zs[t * 66 + k], accz[t]);
    }
  }
#pragma unroll
  for (int t = 0; t < 10; ++t) {
    p.xf[(size_t)t * 131072 + (size_t)bid * 512 + n] = f2b(accx[t]);
    p.zf[(size_t)t * 131072 + (size_t)bid * 512 + n] = f2b(accz[t]);
  }
  __syncthreads();
}

// --------------------------- phase 0a: conversions -------------------------
DEV void phase0a(const Params& p, int gtid) {
  for (int g = gtid; g < 786432; g += NT_ALL) {     // enc/encp 4096 x 192 units
    int row = g / 192;
    int u = g - row * 192;
    int k = u * 8;
    int nsrc = (row & 3) * 1024 + (row >> 2);       // gate-interleaved rows
    const float* s1 = (k < 512) ? (p.e_wih + (size_t)nsrc * 512 + k)
                                : (p.e_whh + (size_t)nsrc * 1024 + (k - 512));
    ((uint4*)p.Wenc)[g] = cvt8(s1);
    const float* s2 = (k < 512) ? (p.p_wih + (size_t)nsrc * 512 + k)
                                : (p.p_whh + (size_t)nsrc * 1024 + (k - 512));
    ((uint4*)p.Wencp)[g] = cvt8(s2);
  }
  for (int g = gtid; g < 524288; g += NT_ALL) {     // dec whh -> Wdec[:,1024:]
    int row = g >> 7, u = g & 127;
    int nsrc = (row & 3) * 1024 + (row >> 2);
    ((uint4*)p.Wdec)[row * 256 + 128 + u] = cvt8(p.d_whh + (size_t)nsrc * 1024 + u * 8);
  }
  for (int g = gtid; g < 262144; g += NT_ALL) {     // dec wih (gate-permuted)
    int row = g >> 6, u = g & 63;
    int nsrc = (row & 3) * 1024 + (row >> 2);
    ((uint4*)p.wihP)[g] = cvt8(p.d_wih + (size_t)nsrc * 512 + u * 8);
  }
  for (int g = gtid; g < 524288; g += NT_ALL) {     // lin_w transpose
    int f = g >> 10, h = g & 1023;
    p.linT[(size_t)h * 512 + f] = f2b(p.lin_w[g]);
  }
  for (int g = gtid; g < 8448; g += NT_ALL)
    ((uint4*)p.tpw)[g] = cvt8(p.tp_w + g * 8);
  for (int g = gtid; g < 4096; g += NT_ALL) {       // enc biases
    int nsrc = (g & 3) * 1024 + (g >> 2);
    p.bias_e[g]  = p.e_bih[nsrc] + p.e_bhh[nsrc];
    p.bias_ep[g] = p.p_bih[nsrc] + p.p_bhh[nsrc];
  }
  for (int g = gtid; g < 32768; g += NT_ALL) {      // bias_d partials (wih@lin_b)
    int cell = g >> 3, sub = g & 7;
    int nsrc = (cell & 3) * 1024 + (cell >> 2);
    const float* wr_ = p.d_wih + (size_t)nsrc * 512 + sub * 64;
    const float* lb = p.lin_b + sub * 64;
    float s = 0.f;
    for (int f = 0; f < 64; ++f) s += wr_[f] * lb[f];
    p.bias_part[g] = s;
  }
  uint4 zz; zz.x = zz.y = zz.z = zz.w = 0u;         // zero h0 for both encoders
  for (int g = gtid; g < 32768; g += NT_ALL) { ((uint4*)p.he)[g] = zz; ((uint4*)p.hp)[g] = zz; }
}

// --------------------------- attention (1 row / block) ---------------------
// LDS: catl @ sm+32768 (43008), cl @ sm+75776 (4096), sc @ sm+79872.
DEV void attention(const Params& p, const u16* hd_prev, const float* cpub,
                   u16* atth_s, int b, int tid, char* sm) {
  u16*   catl = (u16*)(sm + 32768);
  float* cl   = (float*)(sm + 75776);
  float* sc   = (float*)(sm + 79872);
  for (int g = tid; g < 2688; g += NTHR) {
    int t = g >> 7, hu = g & 127;
    const u16* src;
    if (t < 10)       src = p.he + (size_t)(t + 1) * HSTRIDE;
    else if (t == 10) src = hd_prev;
    else              src = p.hp + (size_t)(t - 10) * HSTRIDE;
    ((uint4*)catl)[g] = *(const uint4*)(src + (size_t)b * 1024 + hu * 8);
  }
  for (int g = tid; g < 512; g += NTHR) {
    unsigned long long v = ld_byp(((const unsigned long long*)(cpub + (size_t)b * 1024)) + g);
    ((unsigned long long*)cl)[g] = v;
  }
  __syncthreads();
  const int wv = tid >> 6, l = tid & 63;
  for (int t = wv; t < 21; t += 8) {
    float s = 0.f;
    const u16* cr = catl + t * 1024;
    for (int hh = l; hh < 1024; hh += 64) s += cl[hh] * b2f(cr[hh]);
#pragma unroll
    for (int o = 32; o; o >>= 1) s += __shfl_down(s, o);
    if (l == 0) sc[t] = s;
  }
  __syncthreads();
  float m = -1e30f;
#pragma unroll
  for (int t = 0; t < 21; ++t) m = fmaxf(m, sc[t]);
  float e[21]; float den = 0.f;
#pragma unroll
  for (int t = 0; t < 21; ++t) { e[t] = __expf(sc[t] - m); den += e[t]; }
  float inv = 1.0f / den;
  const int h0 = tid * 2;
  float a0 = 0.f, a1 = 0.f;
#pragma unroll
  for (int t = 0; t < 21; ++t) {
    float w_ = e[t] * inv;
    unsigned v = *(const unsigned*)(catl + t * 1024 + h0);
    a0 += w_ * b2f((u16)(v & 0xffff));
    a1 += w_ * b2f((u16)(v >> 16));
  }
  st_wt(((unsigned*)(atth_s + (size_t)b * 1024)) + tid, pk2(a0, a1));
  __syncthreads();
}

// ------------------------- final projection (1 b / block) ------------------
DEV void finalproj(const Params& p, int b, int tid, char* sm) {
  u16* hl = (u16*)(sm + 32768);           // [25][1024] bf16 = 51200 B
  for (int g = tid; g < 3200; g += NTHR) {
    int t = g >> 7, hu = g & 127;
    ((uint4*)hl)[g] = *(const uint4*)(p.hs + ((size_t)(t * 256 + b)) * 1024 + hu * 8);
  }
  __syncthreads();
  if (tid < 330) {
    int pcol = tid % 66, tg = tid / 66;
    float acc[5] = {0.f, 0.f, 0.f, 0.f, 0.f};
    const u16* wrow = p.tpw + (size_t)pcol * 1024;
    for (int hc = 0; hc < 128; ++hc) {
      uint4 wv4 = ((const uint4*)wrow)[hc];
      float wf[8];
      wf[0] = b2f(wv4.x & 0xffff); wf[1] = b2f(wv4.x >> 16);
      wf[2] = b2f(wv4.y & 0xffff); wf[3] = b2f(wv4.y >> 16);
      wf[4] = b2f(wv4.z & 0xffff); wf[5] = b2f(wv4.z >> 16);
      wf[6] = b2f(wv4.w & 0xffff); wf[7] = b2f(wv4.w >> 16);
#pragma unroll
      for (int r = 0; r < 5; ++r) {
        int t = tg * 5 + r;
        uint4 hv = ((const uint4*)(hl + t * 1024))[hc];
        float s;
        s  = wf[0] * b2f(hv.x & 0xffff) + wf[1] * b2f(hv.x >> 16);
        s += wf[2] * b2f(hv.y & 0xffff) + wf[3] * b2f(hv.y >> 16);
        s += wf[4] * b2f(hv.z & 0xffff) + wf[5] * b2f(hv.z >> 16);
        s += wf[6] * b2f(hv.w & 0xffff) + wf[7] * b2f(hv.w >> 16);
        acc[r] += s;
      }
    }
    float bb = p.tp_b[pcol];
#pragma unroll
    for (int r = 0; r < 5; ++r) {
      int t = tg * 5 + r;
      size_t o = (size_t)b * 1650 + (size_t)t * 66 + pcol;
      p.out[o] = acc[r] + bb + p.resid[o];
    }
  }
}

// ------------------------------- main kernel -------------------------------
__global__ __launch_bounds__(NTHR) void model_kernel(Params p) {
  cg::grid_group gg = cg::this_grid();
  extern __shared__ __align__(16) char sm[];
  const int tid = threadIdx.x;
  const int bid = blockIdx.x;
  const int gtid = bid * NTHR + tid;

  phase0_tf(p, bid, tid, sm);
  phase0a(p, gtid);
  if (bid == 0 && tid < 40) st_wt(&p.bar[tid * 16], 0u);   // reset all counters
  gg.sync();                      // ONLY full-fence sync (flushes phase0 writes)

  // finalize bias_d
  for (int g = gtid; g < 4096; g += NT_ALL) {
    int nsrc = (g & 3) * 1024 + (g >> 2);
    float s = p.d_bih[nsrc] + p.d_bhh[nsrc];
#pragma unroll
    for (int k8 = 0; k8 < 8; ++k8) s += p.bias_part[g * 8 + k8];
    st_wt(&p.bias_d[g], s);
  }

  // P0b: Wdec[:,0:1024] = (gate-permuted dec_wih) @ lin_w  (lin fused)
#pragma unroll 1
  for (int i = 0; i < 4; ++i) {
    int tt = bid * 4 + i;
    int m0w = (tt & 63) << 6;
    int n0w = (tt >> 6) << 6;
    f32x4_t acc[2]; acc[0] = fzero4(); acc[1] = fzero4();
    gemmT(p.wihP, 512, 512, p.wihP, 512, p.linT, 512, 512,
          m0w, n0w, tid, sm, acc);
    wx_store(acc, tid, p.Wdec, m0w, n0w);
  }

  // Geometry: lane = batch group (64 rows), j -> n-tile; j&7 pins XCD slice.
  const int lane = bid >> 6, j = bid & 63;
  const int m0 = lane << 6;
  const int n0 = ((j & 7) * 8 + (j >> 3)) << 6;

  fullbar(p.bar, bid, 32u, tid);  // Wdec + bias_d complete; lanes decouple now

  float ce[2] = {0.f, 0.f}, cp[2] = {0.f, 0.f};   // c in registers, all steps
  unsigned lep = 0;

  // P1: both encoders per t; lanes fully independent from here on
#pragma unroll 1
  for (int t = 0; t < 10; ++t) {
    f32x4_t acc[2]; acc[0] = fzero4(); acc[1] = fzero4();
    gemmT(p.xf + (size_t)t * 131072, 512, 512, p.he + (size_t)t * HSTRIDE, 1024,
          p.Wenc, 1536, 1536, m0, n0, tid, sm, acc);
    lstm_ep(acc, tid, sm, p.bias_e, ce, p.he + (size_t)(t + 1) * HSTRIDE,
            (t == 9) ? p.c_pub : (float*)0, m0, n0);
    acc[0] = fzero4(); acc[1] = fzero4();
    gemmT(p.zf + (size_t)t * 131072, 512, 512, p.hp + (size_t)t * HSTRIDE, 1024,
          p.Wencp, 1536, 1536, m0, n0, tid, sm, acc);
    lstm_ep(acc, tid, sm, p.bias_ep, cp, p.hp + (size_t)(t + 1) * HSTRIDE,
            (float*)0, m0, n0);
    ++lep; lanebar8(p.bar, lane, j, lep * 8u, tid);
  }

  // P3: decoder. att -> gemm1(hd@Wx) -> bar -> gemm2(atth@Whh, accumulate)
  // -> ep -> bar. c continues in ce[].
#pragma unroll 1
  for (int s = 0; s < 25; ++s) {
    const u16* hd_prev = (s == 0) ? (p.he + (size_t)10 * HSTRIDE)
                                  : (p.hs + (size_t)(s - 1) * HSTRIDE);
    u16* atth_s = p.atth + (size_t)s * HSTRIDE;
    attention(p, hd_prev, p.c_pub + (size_t)(s & 1) * 262144, atth_s, bid, tid, sm);
    f32x4_t acc[2]; acc[0] = fzero4(); acc[1] = fzero4();
    gemmT(hd_prev, 1024, 1024, hd_prev, 1024, p.Wdec, 2048, 1024,
          m0, n0, tid, sm, acc);
    ++lep; lanebar8(p.bar, lane, j, lep * 8u, tid);   // atth from all 64 blocks
    gemmT(atth_s, 1024, 1024, atth_s, 1024, p.Wdec + 1024, 2048, 1024,
          m0, n0, tid, sm, acc);
    lstm_ep(acc, tid, sm, p.bias_d, ce, p.hs + (size_t)s * HSTRIDE,
            p.c_pub + (size_t)((s + 1) & 1) * 262144, m0, n0);
    ++lep; lanebar8(p.bar, lane, j, lep * 8u, tid);   // hs[s], c_pub ready
  }

  // P4: out = dec_h @ tp_w.T + tp_b + for_resid
  finalproj(p, bid, tid, sm);
}

// ------------------------------- host launch -------------------------------
extern "C" void kernel_launch(void* const* d_in, const int* in_sizes, int n_in,
                              void* d_out, int out_size, void* d_ws, size_t ws_size,
                              hipStream_t stream) {
  (void)in_sizes; (void)n_in; (void)out_size;
  Params P;
  P.x     = (const float*)d_in[0];
  P.z     = (const float*)d_in[1];
  P.resid = (const float*)d_in[2];
  P.tf_w  = (const float*)d_in[3];
  P.tf_b  = (const float*)d_in[4];
  P.e_wih = (const float*)d_in[5];
  P.e_whh = (const float*)d_in[6];
  P.e_bih = (const float*)d_in[7];
  P.e_bhh = (const float*)d_in[8];
  P.p_wih = (const float*)d_in[9];
  P.p_whh = (const float*)d_in[10];
  P.p_bih = (const float*)d_in[11];
  P.p_bhh = (const float*)d_in[12];
  P.d_wih = (const float*)d_in[13];
  P.d_whh = (const float*)d_in[14];
  P.d_bih = (const float*)d_in[15];
  P.d_bhh = (const float*)d_in[16];
  P.lin_w = (const float*)d_in[17];
  P.lin_b = (const float*)d_in[18];
  P.tp_w  = (const float*)d_in[19];
  P.tp_b  = (const float*)d_in[20];

  char* w = (char*)d_ws;
  size_t o = 0;
  auto take = [&](size_t bytes) { char* r = w + o; o = (o + bytes + 255) & ~(size_t)255; return r; };
  P.Wenc  = (u16*)take(4096ull * 1536 * 2);
  P.Wencp = (u16*)take(4096ull * 1536 * 2);
  P.Wdec  = (u16*)take(4096ull * 2048 * 2);
  P.wihP  = (u16*)take(4096ull * 512 * 2);
  P.linT  = (u16*)take(1024ull * 512 * 2);
  P.tpw   = (u16*)take(66ull * 1024 * 2);
  P.bias_e    = (float*)take(4096 * 4);
  P.bias_ep   = (float*)take(4096 * 4);
  P.bias_d    = (float*)take(4096 * 4);
  P.bias_part = (float*)take(32768 * 4);
  P.xf  = (u16*)take(10ull * 256 * 512 * 2);
  P.zf  = (u16*)take(10ull * 256 * 512 * 2);
  P.he  = (u16*)take(11ull * 256 * 1024 * 2);
  P.hp  = (u16*)take(11ull * 256 * 1024 * 2);
  P.hs  = (u16*)take(25ull * 256 * 1024 * 2);
  P.atth = (u16*)take(25ull * 256 * 1024 * 2);
  P.c_pub = (float*)take(2ull * 256 * 1024 * 4);
  P.bar   = (unsigned*)take(40 * 64);
  P.out = (float*)d_out;

  if (o > ws_size) return;  // workspace too small: fail cleanly, no corruption

  hipFuncSetAttribute((const void*)model_kernel,
                      hipFuncAttributeMaxDynamicSharedMemorySize, SMEM_BYTES);

  void* args[] = { &P };
  hipLaunchCooperativeKernel((const void*)model_kernel, dim3(NBLK, 1, 1),
                             dim3(NTHR, 1, 1), args, SMEM_BYTES, stream);
}

// Round 8
// 840.470 us; speedup vs baseline: 1.9756x; 1.9756x over previous
//
#include <hip/hip_runtime.h>
#include <hip/hip_bf16.h>
#include <hip/hip_cooperative_groups.h>

namespace cg = cooperative_groups;

#define DEV __device__ __forceinline__

typedef unsigned short u16;
typedef short bf16x8_t __attribute__((ext_vector_type(8)));
typedef float f32x4_t __attribute__((ext_vector_type(4)));

// Model dims: B=256 H=1024 F=512 P=66 T_IN=10 T_OUT=25, gates 4H=4096
// enc K = F+H = 1536 (64x128 tiles, grid halves); dec: two K=1024 gemms, 64x64
constexpr int NBLK = 256;
constexpr int NTHR = 512;
constexpr int NT_ALL = NBLK * NTHR;
constexpr size_t HSTRIDE = 256 * 1024;
constexpr int SMEM_BYTES = 98304;

struct Params {
  const float *x, *z, *resid, *tf_w, *tf_b;
  const float *e_wih, *e_whh, *e_bih, *e_bhh;
  const float *p_wih, *p_whh, *p_bih, *p_bhh;
  const float *d_wih, *d_whh, *d_bih, *d_bhh;
  const float *lin_w, *lin_b, *tp_w, *tp_b;
  u16 *Wenc, *Wencp, *Wdec, *wihP, *linT, *tpw;
  float *bias_e, *bias_ep, *bias_d, *bias_part;
  u16 *xf, *zf;
  u16 *he, *hp;            // 11 step-buffers each
  u16 *hs;                 // 25 decoder h buffers
  u16 *atth;               // 25 step-buffers
  float *c_pub;            // 2 ping-pong f32 [256][1024]
  unsigned *bar;           // ctr[i*16]: 0..7 full, 8..15 enc groups, 16..47 lanes
  float *out;
};

DEV float b2f(u16 v) { unsigned u = ((unsigned)v) << 16; float f; __builtin_memcpy(&f, &u, 4); return f; }
DEV u16 f2b(float f) {
  unsigned u; __builtin_memcpy(&u, &f, 4);
  unsigned r = u + 0x7fffu + ((u >> 16) & 1u);   // RNE
  return (u16)(r >> 16);
}
DEV unsigned pk2(float a, float b) { return (unsigned)f2b(a) | ((unsigned)f2b(b) << 16); }
DEV uint4 cvt8(const float* s) {
  float4 a = *(const float4*)s;
  float4 b = *(const float4*)(s + 4);
  uint4 r;
  r.x = pk2(a.x, a.y); r.y = pk2(a.z, a.w);
  r.z = pk2(b.x, b.y); r.w = pk2(b.z, b.w);
  return r;
}
DEV float sigm(float x) { return 1.0f / (1.0f + __expf(-x)); }
DEV f32x4_t fzero4() { f32x4_t v = {0.f, 0.f, 0.f, 0.f}; return v; }

DEV void gll16(const void* g, void* l) {
  __builtin_amdgcn_global_load_lds(
      (const __attribute__((address_space(1))) void*)g,
      (__attribute__((address_space(3))) void*)l, 16, 0, 0);
}

template <typename T> DEV void st_wt(T* p, T v) {
  __hip_atomic_store(p, v, __ATOMIC_RELAXED, __HIP_MEMORY_SCOPE_AGENT);
}
template <typename T> DEV T ld_byp(const T* p) {
  return __hip_atomic_load(p, __ATOMIC_RELAXED, __HIP_MEMORY_SCOPE_AGENT);
}

// ---- fence-free barriers: monotonic counters, no cache flush ----
DEV void fullbar(unsigned* ctrs, int bid, unsigned tgt, int tid) {
  asm volatile("s_waitcnt vmcnt(0)" ::: "memory");
  __syncthreads();
  if (tid == 0) atomicAdd(&ctrs[(bid & 7) * 16], 1u);
  if (tid < 8) { while (ld_byp(&ctrs[tid * 16]) < tgt) __builtin_amdgcn_s_sleep(2); }
  __syncthreads();
}
DEV void gbar(unsigned* ctrs, int cbase, int myidx, unsigned tgt, int tid) {
  asm volatile("s_waitcnt vmcnt(0)" ::: "memory");
  __syncthreads();
  if (tid == 0) atomicAdd(&ctrs[(cbase + myidx) * 16], 1u);
  if (tid < 4) { while (ld_byp(&ctrs[(cbase + tid) * 16]) < tgt) __builtin_amdgcn_s_sleep(2); }
  __syncthreads();
}
DEV void lanebar8(unsigned* ctrs, int lane, int j, unsigned tgt, int tid) {
  asm volatile("s_waitcnt vmcnt(0)" ::: "memory");
  __syncthreads();
  if (tid == 0) atomicAdd(&ctrs[(16 + lane * 8 + (j & 7)) * 16], 1u);
  if (tid < 8) { while (ld_byp(&ctrs[(16 + lane * 8 + tid) * 16]) < tgt) __builtin_amdgcn_s_sleep(1); }
  __syncthreads();
}

// ------------- 64m x 128n tile bf16 GEMM, 8 waves of 32x32 (encoders) ------
// LDS: lA = sm[0..32K) 4 slots x 8KB; lB = sm[32K..96K) 4 slots x 16KB.
// slot(ks) = (ks+2)&3. Source-side XOR swizzle + same XOR on ds_read_b128.
// PM: 0 = stage A+B slots 0,1 at entry; 1 = caller prestaged A+B slots 0,1
// (prestaged data already DRAINED to LDS by a prior barrier's vmcnt(0)).
template <int PM>
DEV void gemm128(const u16* __restrict__ xa, int ldx, int xcols,
                 const u16* __restrict__ ha, int ldh,
                 const u16* __restrict__ wsrc, int ldw, int K,
                 int m0, int n0, int tid, char* sm, f32x4_t acc[4]) {
  char* lA = sm;
  char* lB = sm + 32768;
  const int NK = K >> 6;
  const int row = tid >> 3;
  const int usw = ((tid & 7) ^ (row & 7)) * 8;
  const int wv = tid >> 6;
  char* laD = lA + (wv << 10);
  char* lbD = lB + (wv << 10);
  const u16* aX = xa + (size_t)(m0 + row) * ldx + usw;
  const u16* aH = ha + (size_t)(m0 + row) * ldh + usw - xcols;
  const u16* bW0 = wsrc + (size_t)(n0 + row) * ldw + usw;
  const u16* bW1 = bW0 + (size_t)64 * ldw;

  auto sA = [&](int ks) {
    const int k0 = ks << 6;
    const u16* g = (k0 < xcols) ? (aX + k0) : (aH + k0);
    gll16(g, laD + (((ks + 2) & 3) << 13));
  };
  auto sB = [&](int ks) {
    const int k0 = ks << 6;
    const int so = ((ks + 2) & 3) << 14;
    gll16(bW0 + k0, lbD + so);
    gll16(bW1 + k0, lbD + so + 8192);
  };

  const int l = tid & 63, l15 = l & 15, lhi = l >> 4;
  const int wr = wv >> 2, wc = wv & 3;   // 2m x 4n wave grid, 32x32 wave tile
  const int rA0 = wr * 32 + l15, rA1 = rA0 + 16;
  const int nB0 = wc * 32 + l15, nB1 = nB0 + 16;
  const int a00 = rA0 * 128 + ((lhi ^ (rA0 & 7)) << 4);
  const int a01 = rA0 * 128 + (((lhi + 4) ^ (rA0 & 7)) << 4);
  const int a10 = rA1 * 128 + ((lhi ^ (rA1 & 7)) << 4);
  const int a11 = rA1 * 128 + (((lhi + 4) ^ (rA1 & 7)) << 4);
  const int b00 = nB0 * 128 + ((lhi ^ (nB0 & 7)) << 4);
  const int b01 = nB0 * 128 + (((lhi + 4) ^ (nB0 & 7)) << 4);
  const int b10 = nB1 * 128 + ((lhi ^ (nB1 & 7)) << 4);
  const int b11 = nB1 * 128 + (((lhi + 4) ^ (nB1 & 7)) << 4);

  if (PM == 0) { sA(0); sB(0); sA(1); sB(1); }

#pragma unroll 1
  for (int ks = 0; ks < NK; ++ks) {
    if (ks + 2 < NK) { sA(ks + 2); sB(ks + 2); }
    if (ks + 2 < NK)        asm volatile("s_waitcnt vmcnt(6)" ::: "memory");
    else if (ks + 2 == NK)  asm volatile("s_waitcnt vmcnt(3)" ::: "memory");
    else                    asm volatile("s_waitcnt vmcnt(0)" ::: "memory");
    __builtin_amdgcn_s_barrier();
    const char* A  = lA + (((ks + 2) & 3) << 13);
    const char* Bq = lB + (((ks + 2) & 3) << 14);
#pragma unroll
    for (int kh = 0; kh < 2; ++kh) {
      bf16x8_t va0 = *(const bf16x8_t*)(A + (kh ? a01 : a00));
      bf16x8_t va1 = *(const bf16x8_t*)(A + (kh ? a11 : a10));
      bf16x8_t vb0 = *(const bf16x8_t*)(Bq + (kh ? b01 : b00));
      bf16x8_t vb1 = *(const bf16x8_t*)(Bq + (kh ? b11 : b10));
      acc[0] = __builtin_amdgcn_mfma_f32_16x16x32_bf16(va0, vb0, acc[0], 0, 0, 0);
      acc[1] = __builtin_amdgcn_mfma_f32_16x16x32_bf16(va0, vb1, acc[1], 0, 0, 0);
      acc[2] = __builtin_amdgcn_mfma_f32_16x16x32_bf16(va1, vb0, acc[2], 0, 0, 0);
      acc[3] = __builtin_amdgcn_mfma_f32_16x16x32_bf16(va1, vb1, acc[3], 0, 0, 0);
    }
  }
  asm volatile("s_waitcnt lgkmcnt(0)" ::: "memory");
  __builtin_amdgcn_s_barrier();
}

// Prestage helpers for gemm128 (must match its addressing/slot map exactly)
DEV void preA128(const u16* src, int lds_, int m0, int tid, char* sm, int ks) {
  const int row = tid >> 3, usw = ((tid & 7) ^ (row & 7)) * 8, wv = tid >> 6;
  gll16(src + (size_t)(m0 + row) * lds_ + (ks << 6) + usw,
        sm + (wv << 10) + (((ks + 2) & 3) << 13));
}
DEV void preB128(const u16* w, int ldw, int n0, int tid, char* sm, int ks) {
  const int row = tid >> 3, usw = ((tid & 7) ^ (row & 7)) * 8, wv = tid >> 6;
  char* d = sm + 32768 + (wv << 10) + (((ks + 2) & 3) << 14);
  gll16(w + (size_t)(n0 + row) * ldw + (ks << 6) + usw, d);
  gll16(w + (size_t)(n0 + 64 + row) * ldw + (ks << 6) + usw, d + 8192);
}

// ------------- 64x64-tile bf16 GEMM (decoder), B slots 0,1 prestaged -------
// LDS: lB = sm[0..32K) 4 slots x 8K; lA = sm[32K..64K) 4 slots x 8K.
// slot(ks) = ks&3. Caller prestaged B slots 0,1 (drained by a barrier since);
// A staged at entry. B slots 0,1 must survive anything between the prestage
// and this call (attention's catl starts at sm+16384, preserving [0..16K)).
DEV void gemm64d(const u16* __restrict__ a, int lda,
                 const u16* __restrict__ w, int ldw, int K,
                 int m0, int n0, int tid, char* sm, f32x4_t acc[2]) {
  char* lB = sm;
  char* lA = sm + 32768;
  const int NK = K >> 6;
  const int row = tid >> 3, uu = tid & 7;
  const int usw = uu ^ (row & 7);
  const int wv = tid >> 6;
  char* la_base = lA + (wv << 10);
  char* lb_base = lB + (wv << 10);
  const u16* aS = a + (size_t)(m0 + row) * lda + usw * 8;
  const u16* bS = w + (size_t)(n0 + row) * ldw + usw * 8;

  auto stageA = [&](int ks) { gll16(aS + (ks << 6), la_base + ((ks & 3) << 13)); };
  auto stage  = [&](int ks) {
    gll16(aS + (ks << 6), la_base + ((ks & 3) << 13));
    gll16(bS + (ks << 6), lb_base + ((ks & 3) << 13));
  };

  const int l = tid & 63, l15 = l & 15, lhi = l >> 4;
  const int wr = wv >> 1, wc = wv & 1;       // 4x2 wave grid, wave tile 16x32
  const int rA = wr * 16 + l15;
  const int aoff0 = rA * 128 + ((lhi ^ (rA & 7)) << 4);
  const int aoff1 = rA * 128 + (((lhi + 4) ^ (rA & 7)) << 4);
  const int nB0 = wc * 32 + l15, nB1 = nB0 + 16;
  const int boff00 = nB0 * 128 + ((lhi ^ (nB0 & 7)) << 4);
  const int boff01 = nB0 * 128 + (((lhi + 4) ^ (nB0 & 7)) << 4);
  const int boff10 = nB1 * 128 + ((lhi ^ (nB1 & 7)) << 4);
  const int boff11 = nB1 * 128 + (((lhi + 4) ^ (nB1 & 7)) << 4);

  stageA(0); stageA(1);

#pragma unroll 1
  for (int ks = 0; ks < NK; ++ks) {
    if (ks + 2 < NK) stage(ks + 2);
    if (ks == 0)            asm volatile("s_waitcnt vmcnt(3)" ::: "memory");
    else if (ks + 2 < NK)   asm volatile("s_waitcnt vmcnt(4)" ::: "memory");
    else if (ks + 2 == NK)  asm volatile("s_waitcnt vmcnt(2)" ::: "memory");
    else                    asm volatile("s_waitcnt vmcnt(0)" ::: "memory");
    __builtin_amdgcn_s_barrier();
    const char* A  = lA + ((ks & 3) << 13);
    const char* Bb = lB + ((ks & 3) << 13);
    bf16x8_t a0  = *(const bf16x8_t*)(A + aoff0);
    bf16x8_t a1  = *(const bf16x8_t*)(A + aoff1);
    bf16x8_t b00 = *(const bf16x8_t*)(Bb + boff00);
    bf16x8_t b01 = *(const bf16x8_t*)(Bb + boff01);
    bf16x8_t b10 = *(const bf16x8_t*)(Bb + boff10);
    bf16x8_t b11 = *(const bf16x8_t*)(Bb + boff11);
    acc[0] = __builtin_amdgcn_mfma_f32_16x16x32_bf16(a0, b00, acc[0], 0, 0, 0);
    acc[0] = __builtin_amdgcn_mfma_f32_16x16x32_bf16(a1, b01, acc[0], 0, 0, 0);
    acc[1] = __builtin_amdgcn_mfma_f32_16x16x32_bf16(a0, b10, acc[1], 0, 0, 0);
    acc[1] = __builtin_amdgcn_mfma_f32_16x16x32_bf16(a1, b11, acc[1], 0, 0, 0);
  }
  asm volatile("s_waitcnt lgkmcnt(0)" ::: "memory");
  __builtin_amdgcn_s_barrier();
}

// Prestage B slots 0,1 for gemm64d ([0..16K), survives attention)
DEV void preB64(const u16* w, int ldw, int n0, int tid, char* sm, int ks) {
  const int row = tid >> 3, usw = (tid & 7) ^ (row & 7), wv = tid >> 6;
  gll16(w + (size_t)(n0 + row) * ldw + (ks << 6) + usw * 8,
        sm + (wv << 10) + ((ks & 3) << 13));
}

// --------- LSTM epilogue, enc variant: [64][128] f32 overlay @ sm[0..32K) ---
DEV void lstm_ep128(const f32x4_t acc[4], int tid, char* sm,
                    const float* __restrict__ bias, float cc[4],
                    u16* __restrict__ hw, float* __restrict__ cpub,
                    int m0, int n0) {
  float* gl = (float*)sm;
  const int l = tid & 63, l15 = l & 15, lhi = l >> 4;
  const int wv = tid >> 6, wr = wv >> 2, wc = wv & 3;
#pragma unroll
  for (int mf = 0; mf < 2; ++mf)
#pragma unroll
    for (int nf = 0; nf < 2; ++nf)
#pragma unroll
      for (int qq = 0; qq < 4; ++qq)
        gl[(wr * 32 + mf * 16 + lhi * 4 + qq) * 128 + wc * 32 + nf * 16 + l15] =
            acc[mf * 2 + nf][qq];
  __syncthreads();
#pragma unroll
  for (int it = 0; it < 4; ++it) {
    int idx = it * 512 + tid;            // 2048 items: 64 rows x 32 j
    int r = idx >> 5, jj = idx & 31;
    f32x4_t g4 = *(const f32x4_t*)(gl + r * 128 + jj * 4);
    f32x4_t b4 = *(const f32x4_t*)(bias + n0 + jj * 4);
    float ig = sigm(g4[0] + b4[0]);
    float fg = sigm(g4[1] + b4[1]);
    float g_ = tanhf(g4[2] + b4[2]);
    float og = sigm(g4[3] + b4[3]);
    float cn = fg * cc[it] + ig * g_;
    cc[it] = cn;
    float hn = og * tanhf(cn);
    size_t off = (size_t)(m0 + r) * 1024 + (n0 >> 2) + jj;
    st_wt(&hw[off], f2b(hn));
    if (cpub) st_wt(&cpub[off], cn);
  }
  __syncthreads();
}

// --------- LSTM epilogue, dec variant: [64][64] f32 overlay @ sm+49152 ------
DEV void lstm_ep64(const f32x4_t acc[2], int tid, char* sm,
                   const float* __restrict__ bias, float cc[2],
                   const float* __restrict__ cinit,
                   u16* __restrict__ hw, float* __restrict__ cpub,
                   int m0, int n0) {
  float* gl = (float*)(sm + 49152);
  const int l = tid & 63, l15 = l & 15, lhi = l >> 4;
  const int wv = tid >> 6, wr = wv >> 1, wc = wv & 1;
#pragma unroll
  for (int jf = 0; jf < 2; ++jf)
#pragma unroll
    for (int qq = 0; qq < 4; ++qq)
      gl[(wr * 16 + lhi * 4 + qq) * 64 + wc * 32 + jf * 16 + l15] = acc[jf][qq];
  __syncthreads();
#pragma unroll
  for (int it = 0; it < 2; ++it) {
    int idx = it * 512 + tid;           // 1024 items: 64 rows x 16 j
    int r = idx >> 4, jj = idx & 15;
    f32x4_t g4 = *(const f32x4_t*)(gl + r * 64 + jj * 4);
    f32x4_t b4 = *(const f32x4_t*)(bias + n0 + jj * 4);
    float ig = sigm(g4[0] + b4[0]);
    float fg = sigm(g4[1] + b4[1]);
    float g_ = tanhf(g4[2] + b4[2]);
    float og = sigm(g4[3] + b4[3]);
    size_t off = (size_t)(m0 + r) * 1024 + (n0 >> 2) + jj;
    float cold = cinit ? ld_byp(cinit + off) : cc[it];
    float cn = fg * cold + ig * g_;
    cc[it] = cn;
    float hn = og * tanhf(cn);
    st_wt(&hw[off], f2b(hn));
    if (cpub) st_wt(&cpub[off], cn);
  }
  __syncthreads();
}

DEV void wx_store(const f32x4_t acc[4], int tid, u16* __restrict__ Wdec,
                  int m0, int n0) {
  const int l = tid & 63, l15 = l & 15, lhi = l >> 4;
  const int wv = tid >> 6, wr = wv >> 2, wc = wv & 3;
#pragma unroll
  for (int mf = 0; mf < 2; ++mf)
#pragma unroll
    for (int nf = 0; nf < 2; ++nf)
#pragma unroll
      for (int qq = 0; qq < 4; ++qq) {
        int r = m0 + wr * 32 + mf * 16 + lhi * 4 + qq;
        int c = n0 + wc * 32 + nf * 16 + l15;
        st_wt(&Wdec[(size_t)r * 2048 + c], f2b(acc[mf * 2 + nf][qq]));
      }
}

// ------------------- phase 0: ToFeature (block-cooperative) ----------------
DEV void phase0_tf(const Params& p, int bid, int tid, char* sm) {
  float* xs = (float*)sm;            // [10][66]
  float* zs = (float*)(sm + 2688);
  for (int g = tid; g < 660; g += NTHR) {
    int t = g / 66, qd = g - t * 66;
    xs[g] = p.x[((size_t)bid * 10 + t) * 66 + qd];
    zs[g] = p.z[((size_t)bid * 10 + t) * 66 + qd];
  }
  __syncthreads();
  const int n = tid;
  float accx[10], accz[10];
  float bn = p.tf_b[n];
#pragma unroll
  for (int t = 0; t < 10; ++t) { accx[t] = bn; accz[t] = bn; }
  const float* wrow = p.tf_w + (size_t)n * 66;
  for (int k = 0; k < 66; ++k) {
    float wk = wrow[k];
#pragma unroll
    for (int t = 0; t < 10; ++t) {
      accx[t] = fmaf(wk, xs[t * 66 + k], accx[t]);
      accz[t] = fmaf(wk, zs[t * 66 + k], accz[t]);
    }
  }
#pragma unroll
  for (int t = 0; t < 10; ++t) {
    p.xf[(size_t)t * 131072 + (size_t)bid * 512 + n] = f2b(accx[t]);
    p.zf[(size_t)t * 131072 + (size_t)bid * 512 + n] = f2b(accz[t]);
  }
  __syncthreads();
}

// --------------------------- phase 0a: conversions -------------------------
DEV void phase0a(const Params& p, int gtid) {
  for (int g = gtid; g < 786432; g += NT_ALL) {     // enc/encp 4096 x 192 units
    int row = g / 192;
    int u = g - row * 192;
    int k = u * 8;
    int nsrc = (row & 3) * 1024 + (row >> 2);       // gate-interleaved rows
    const float* s1 = (k < 512) ? (p.e_wih + (size_t)nsrc * 512 + k)
                                : (p.e_whh + (size_t)nsrc * 1024 + (k - 512));
    ((uint4*)p.Wenc)[g] = cvt8(s1);
    const float* s2 = (k < 512) ? (p.p_wih + (size_t)nsrc * 512 + k)
                                : (p.p_whh + (size_t)nsrc * 1024 + (k - 512));
    ((uint4*)p.Wencp)[g] = cvt8(s2);
  }
  for (int g = gtid; g < 524288; g += NT_ALL) {     // dec whh -> Wdec[:,1024:]
    int row = g >> 7, u = g & 127;
    int nsrc = (row & 3) * 1024 + (row >> 2);
    ((uint4*)p.Wdec)[row * 256 + 128 + u] = cvt8(p.d_whh + (size_t)nsrc * 1024 + u * 8);
  }
  for (int g = gtid; g < 262144; g += NT_ALL) {     // dec wih (gate-permuted)
    int row = g >> 6, u = g & 63;
    int nsrc = (row & 3) * 1024 + (row >> 2);
    ((uint4*)p.wihP)[g] = cvt8(p.d_wih + (size_t)nsrc * 512 + u * 8);
  }
  for (int g = gtid; g < 524288; g += NT_ALL) {     // lin_w transpose
    int f = g >> 10, h = g & 1023;
    p.linT[(size_t)h * 512 + f] = f2b(p.lin_w[g]);
  }
  for (int g = gtid; g < 8448; g += NT_ALL)
    ((uint4*)p.tpw)[g] = cvt8(p.tp_w + g * 8);
  for (int g = gtid; g < 4096; g += NT_ALL) {       // enc biases
    int nsrc = (g & 3) * 1024 + (g >> 2);
    p.bias_e[g]  = p.e_bih[nsrc] + p.e_bhh[nsrc];
    p.bias_ep[g] = p.p_bih[nsrc] + p.p_bhh[nsrc];
  }
  for (int g = gtid; g < 32768; g += NT_ALL) {      // bias_d partials (wih@lin_b)
    int cell = g >> 3, sub = g & 7;
    int nsrc = (cell & 3) * 1024 + (cell >> 2);
    const float* wr_ = p.d_wih + (size_t)nsrc * 512 + sub * 64;
    const float* lb = p.lin_b + sub * 64;
    float s = 0.f;
    for (int f = 0; f < 64; ++f) s += wr_[f] * lb[f];
    p.bias_part[g] = s;
  }
  uint4 zz; zz.x = zz.y = zz.z = zz.w = 0u;         // zero h0 for both encoders
  for (int g = gtid; g < 32768; g += NT_ALL) { ((uint4*)p.he)[g] = zz; ((uint4*)p.hp)[g] = zz; }
}

// --------------------------- attention (1 row / block) ---------------------
// LDS: catl @ sm+16384 (43008 B -> ends 59392), cl @ 59392, sc @ 63488.
// Preserves gemm64d's prestaged B slots 0,1 at sm[0..16384).
DEV void attention(const Params& p, const u16* hd_prev, const float* cpub,
                   u16* atth_s, int b, int tid, char* sm) {
  u16*   catl = (u16*)(sm + 16384);
  float* cl   = (float*)(sm + 59392);
  float* sc   = (float*)(sm + 63488);
  for (int g = tid; g < 2688; g += NTHR) {
    int t = g >> 7, hu = g & 127;
    const u16* src;
    if (t < 10)       src = p.he + (size_t)(t + 1) * HSTRIDE;
    else if (t == 10) src = hd_prev;
    else              src = p.hp + (size_t)(t - 10) * HSTRIDE;
    ((uint4*)catl)[g] = *(const uint4*)(src + (size_t)b * 1024 + hu * 8);
  }
  for (int g = tid; g < 512; g += NTHR) {
    unsigned long long v = ld_byp(((const unsigned long long*)(cpub + (size_t)b * 1024)) + g);
    ((unsigned long long*)cl)[g] = v;
  }
  __syncthreads();
  const int wv = tid >> 6, l = tid & 63;
  for (int t = wv; t < 21; t += 8) {
    float s = 0.f;
    const u16* cr = catl + t * 1024;
    for (int hh = l; hh < 1024; hh += 64) s += cl[hh] * b2f(cr[hh]);
#pragma unroll
    for (int o = 32; o; o >>= 1) s += __shfl_down(s, o);
    if (l == 0) sc[t] = s;
  }
  __syncthreads();
  float m = -1e30f;
#pragma unroll
  for (int t = 0; t < 21; ++t) m = fmaxf(m, sc[t]);
  float e[21]; float den = 0.f;
#pragma unroll
  for (int t = 0; t < 21; ++t) { e[t] = __expf(sc[t] - m); den += e[t]; }
  float inv = 1.0f / den;
  const int h0 = tid * 2;
  float a0 = 0.f, a1 = 0.f;
#pragma unroll
  for (int t = 0; t < 21; ++t) {
    float w_ = e[t] * inv;
    unsigned v = *(const unsigned*)(catl + t * 1024 + h0);
    a0 += w_ * b2f((u16)(v & 0xffff));
    a1 += w_ * b2f((u16)(v >> 16));
  }
  st_wt(((unsigned*)(atth_s + (size_t)b * 1024)) + tid, pk2(a0, a1));
  __syncthreads();   // catl reads done before gemm1 stages into this region
}

// ------------------------- final projection (1 b / block) ------------------
DEV void finalproj(const Params& p, int b, int tid, char* sm) {
  u16* hl = (u16*)sm;                     // [25][1024] bf16 = 51200 B
  for (int g = tid; g < 3200; g += NTHR) {
    int t = g >> 7, hu = g & 127;
    ((uint4*)hl)[g] = *(const uint4*)(p.hs + ((size_t)(t * 256 + b)) * 1024 + hu * 8);
  }
  __syncthreads();
  if (tid < 330) {
    int pcol = tid % 66, tg = tid / 66;
    float acc[5] = {0.f, 0.f, 0.f, 0.f, 0.f};
    const u16* wrow = p.tpw + (size_t)pcol * 1024;
    for (int hc = 0; hc < 128; ++hc) {
      uint4 wv4 = ((const uint4*)wrow)[hc];
      float wf[8];
      wf[0] = b2f(wv4.x & 0xffff); wf[1] = b2f(wv4.x >> 16);
      wf[2] = b2f(wv4.y & 0xffff); wf[3] = b2f(wv4.y >> 16);
      wf[4] = b2f(wv4.z & 0xffff); wf[5] = b2f(wv4.z >> 16);
      wf[6] = b2f(wv4.w & 0xffff); wf[7] = b2f(wv4.w >> 16);
#pragma unroll
      for (int r = 0; r < 5; ++r) {
        int t = tg * 5 + r;
        uint4 hv = ((const uint4*)(hl + t * 1024))[hc];
        float s;
        s  = wf[0] * b2f(hv.x & 0xffff) + wf[1] * b2f(hv.x >> 16);
        s += wf[2] * b2f(hv.y & 0xffff) + wf[3] * b2f(hv.y >> 16);
        s += wf[4] * b2f(hv.z & 0xffff) + wf[5] * b2f(hv.z >> 16);
        s += wf[6] * b2f(hv.w & 0xffff) + wf[7] * b2f(hv.w >> 16);
        acc[r] += s;
      }
    }
    float bb = p.tp_b[pcol];
#pragma unroll
    for (int r = 0; r < 5; ++r) {
      int t = tg * 5 + r;
      size_t o = (size_t)b * 1650 + (size_t)t * 66 + pcol;
      p.out[o] = acc[r] + bb + p.resid[o];
    }
  }
}

// ------------------------------- main kernel -------------------------------
__global__ __launch_bounds__(NTHR) void model_kernel(Params p) {
  cg::grid_group gg = cg::this_grid();
  extern __shared__ __align__(16) char sm[];
  const int tid = threadIdx.x;
  const int bid = blockIdx.x;
  const int gtid = bid * NTHR + tid;

  phase0_tf(p, bid, tid, sm);
  phase0a(p, gtid);
  if (bid == 0 && tid < 48) st_wt(&p.bar[tid * 16], 0u);   // reset all counters
  gg.sync();                      // ONLY full-fence sync (flushes phase0 writes)

  // finalize bias_d
  for (int g = gtid; g < 4096; g += NT_ALL) {
    int nsrc = (g & 3) * 1024 + (g >> 2);
    float s = p.d_bih[nsrc] + p.d_bhh[nsrc];
#pragma unroll
    for (int k8 = 0; k8 < 8; ++k8) s += p.bias_part[g * 8 + k8];
    st_wt(&p.bias_d[g], s);
  }

  // P0b: Wdec[:,0:1024] = (gate-permuted dec_wih) @ lin_w  (lin fused)
#pragma unroll 1
  for (int i = 0; i < 2; ++i) {
    int tt = bid * 2 + i;
    int m0w = (tt & 63) << 6;
    int n0w = (tt >> 6) << 7;
    f32x4_t acc[4] = {fzero4(), fzero4(), fzero4(), fzero4()};
    gemm128<0>(p.wihP, 512, 512, p.wihP, 512, p.linT, 512, 512,
               m0w, n0w, tid, sm, acc);
    wx_store(acc, tid, p.Wdec, m0w, n0w);
  }

  // Encoder geometry (grid halves): grp0 = enc(x), grp1 = encp(z)
  const int grp = bid >> 7;
  const int q = bid & 127;
  const int m0e = (q >> 5) << 6;
  const int n0e = (q & 31) << 7;
  const int cb = grp ? 12 : 8;
  const int cidx = q >> 5;

  // Decoder geometry (4 lanes x 64 n-tiles; j&7 pins XCD weight slice)
  const int lane = bid >> 6, j = bid & 63;
  const int m0d = lane << 6;
  const int n0d = ((j & 7) * 8 + (j >> 3)) << 6;

  const u16* xsrc = grp ? p.zf : p.xf;
  const u16* Wg   = grp ? p.Wencp : p.Wenc;
  u16* hbuf       = grp ? p.hp : p.he;
  const float* bias_g = grp ? p.bias_ep : p.bias_e;

  // prestage encoder t=0 (xf/zf + W static), then the post-setup full barrier
  preA128(xsrc, 512, m0e, tid, sm, 0);
  preB128(Wg, 1536, n0e, tid, sm, 0);
  preA128(xsrc, 512, m0e, tid, sm, 1);
  preB128(Wg, 1536, n0e, tid, sm, 1);
  fullbar(p.bar, bid, 32u, tid);

  float cc[4] = {0.f, 0.f, 0.f, 0.f};

  // P1: encoders on independent halves (128-block group barriers)
#pragma unroll 1
  for (int t = 0; t < 10; ++t) {
    f32x4_t acc[4] = {fzero4(), fzero4(), fzero4(), fzero4()};
    gemm128<1>(xsrc + (size_t)t * 131072, 512, 512, hbuf + (size_t)t * HSTRIDE, 1024,
               Wg, 1536, 1536, m0e, n0e, tid, sm, acc);
    lstm_ep128(acc, tid, sm, bias_g, cc, hbuf + (size_t)(t + 1) * HSTRIDE,
               (!grp && t == 9) ? p.c_pub : (float*)0, m0e, n0e);
    if (t < 9) {
      preA128(xsrc + (size_t)(t + 1) * 131072, 512, m0e, tid, sm, 0);
      preB128(Wg, 1536, n0e, tid, sm, 0);
      preA128(xsrc + (size_t)(t + 1) * 131072, 512, m0e, tid, sm, 1);
      preB128(Wg, 1536, n0e, tid, sm, 1);
    } else {
      preB64(p.Wdec, 2048, n0d, tid, sm, 0);    // decode gemm1 B panel
      preB64(p.Wdec, 2048, n0d, tid, sm, 1);
    }
    gbar(p.bar, cb, cidx, (unsigned)(t + 1) * 32, tid);
  }
  fullbar(p.bar, bid, 64u, tid);

  // P3: decoder on all 256 blocks. att -> gemm1(hd@Wx) -> bar -> gemm2(atth@
  // Whh, accumulate) -> ep -> bar. c starts from c_pub (s==0), then registers.
  float cd[2] = {0.f, 0.f};
  unsigned lep = 0;
#pragma unroll 1
  for (int s = 0; s < 25; ++s) {
    const u16* hd_prev = (s == 0) ? (p.he + (size_t)10 * HSTRIDE)
                                  : (p.hs + (size_t)(s - 1) * HSTRIDE);
    u16* atth_s = p.atth + (size_t)s * HSTRIDE;
    attention(p, hd_prev, p.c_pub + (size_t)(s & 1) * 262144, atth_s, bid, tid, sm);
    f32x4_t acc[2]; acc[0] = fzero4(); acc[1] = fzero4();
    gemm64d(hd_prev, 1024, p.Wdec, 2048, 1024, m0d, n0d, tid, sm, acc);
    preB64(p.Wdec + 1024, 2048, n0d, tid, sm, 0);   // gemm2 B panel
    preB64(p.Wdec + 1024, 2048, n0d, tid, sm, 1);
    ++lep; lanebar8(p.bar, lane, j, lep * 8u, tid); // atth ready (drains pre)
    gemm64d(atth_s, 1024, p.Wdec + 1024, 2048, 1024, m0d, n0d, tid, sm, acc);
    lstm_ep64(acc, tid, sm, p.bias_d, cd,
              (s == 0) ? p.c_pub : (const float*)0,
              p.hs + (size_t)s * HSTRIDE,
              p.c_pub + (size_t)((s + 1) & 1) * 262144, m0d, n0d);
    if (s < 24) {
      preB64(p.Wdec, 2048, n0d, tid, sm, 0);        // next step gemm1 B panel
      preB64(p.Wdec, 2048, n0d, tid, sm, 1);
    }
    ++lep; lanebar8(p.bar, lane, j, lep * 8u, tid); // hs[s], c_pub ready
  }

  // P4: out = dec_h @ tp_w.T + tp_b + for_resid
  finalproj(p, bid, tid, sm);
}

// ------------------------------- host launch -------------------------------
extern "C" void kernel_launch(void* const* d_in, const int* in_sizes, int n_in,
                              void* d_out, int out_size, void* d_ws, size_t ws_size,
                              hipStream_t stream) {
  (void)in_sizes; (void)n_in; (void)out_size;
  Params P;
  P.x     = (const float*)d_in[0];
  P.z     = (const float*)d_in[1];
  P.resid = (const float*)d_in[2];
  P.tf_w  = (const float*)d_in[3];
  P.tf_b  = (const float*)d_in[4];
  P.e_wih = (const float*)d_in[5];
  P.e_whh = (const float*)d_in[6];
  P.e_bih = (const float*)d_in[7];
  P.e_bhh = (const float*)d_in[8];
  P.p_wih = (const float*)d_in[9];
  P.p_whh = (const float*)d_in[10];
  P.p_bih = (const float*)d_in[11];
  P.p_bhh = (const float*)d_in[12];
  P.d_wih = (const float*)d_in[13];
  P.d_whh = (const float*)d_in[14];
  P.d_bih = (const float*)d_in[15];
  P.d_bhh = (const float*)d_in[16];
  P.lin_w = (const float*)d_in[17];
  P.lin_b = (const float*)d_in[18];
  P.tp_w  = (const float*)d_in[19];
  P.tp_b  = (const float*)d_in[20];

  char* w = (char*)d_ws;
  size_t o = 0;
  auto take = [&](size_t bytes) { char* r = w + o; o = (o + bytes + 255) & ~(size_t)255; return r; };
  P.Wenc  = (u16*)take(4096ull * 1536 * 2);
  P.Wencp = (u16*)take(4096ull * 1536 * 2);
  P.Wdec  = (u16*)take(4096ull * 2048 * 2);
  P.wihP  = (u16*)take(4096ull * 512 * 2);
  P.linT  = (u16*)take(1024ull * 512 * 2);
  P.tpw   = (u16*)take(66ull * 1024 * 2);
  P.bias_e    = (float*)take(4096 * 4);
  P.bias_ep   = (float*)take(4096 * 4);
  P.bias_d    = (float*)take(4096 * 4);
  P.bias_part = (float*)take(32768 * 4);
  P.xf  = (u16*)take(10ull * 256 * 512 * 2);
  P.zf  = (u16*)take(10ull * 256 * 512 * 2);
  P.he  = (u16*)take(11ull * 256 * 1024 * 2);
  P.hp  = (u16*)take(11ull * 256 * 1024 * 2);
  P.hs  = (u16*)take(25ull * 256 * 1024 * 2);
  P.atth = (u16*)take(25ull * 256 * 1024 * 2);
  P.c_pub = (float*)take(2ull * 256 * 1024 * 4);
  P.bar   = (unsigned*)take(48 * 64);
  P.out = (float*)d_out;

  if (o > ws_size) return;  // workspace too small: fail cleanly, no corruption

  hipFuncSetAttribute((const void*)model_kernel,
                      hipFuncAttributeMaxDynamicSharedMemorySize, SMEM_BYTES);

  void* args[] = { &P };
  hipLaunchCooperativeKernel((const void*)model_kernel, dim3(NBLK, 1, 1),
                             dim3(NTHR, 1, 1), args, SMEM_BYTES, stream);
}

// Round 9
// 735.633 us; speedup vs baseline: 2.2572x; 1.1425x over previous
//
#include <hip/hip_runtime.h>
#include <hip/hip_bf16.h>
#include <hip/hip_cooperative_groups.h>

namespace cg = cooperative_groups;

#define DEV __device__ __forceinline__

typedef unsigned short u16;
typedef short bf16x8_t __attribute__((ext_vector_type(8)));
typedef float f32x4_t __attribute__((ext_vector_type(4)));

// Model dims: B=256 H=1024 F=512 P=66 T_IN=10 T_OUT=25, gates 4H=4096
// enc K = F+H = 1536 (64x128 tiles, grid halves); dec: two K=1024 gemms, 64x64
constexpr int NBLK = 256;
constexpr int NTHR = 512;
constexpr int NT_ALL = NBLK * NTHR;
constexpr size_t HSTRIDE = 256 * 1024;
// LDS map (144KB dynamic):
//   [0,32K)      B slots (dec) / lA (enc gemm128) / ep128+finalproj overlay
//   [32K,64K)    A slots (dec) / part of lB (enc gemm128 lB = [32K,96K))
//   [64K,80K)    dec epilogue overlay [64][64] f32
//   [96K,139K)   persistent catl (21 x 1024 bf16), loaded once before decode
//   [138K+]      cl (4KB) + sc
constexpr int SMEM_BYTES = 147456;
constexpr int CATL_OFF = 98304;
constexpr int CL_OFF   = 141312;
constexpr int SC_OFF   = 145408;

struct Params {
  const float *x, *z, *resid, *tf_w, *tf_b;
  const float *e_wih, *e_whh, *e_bih, *e_bhh;
  const float *p_wih, *p_whh, *p_bih, *p_bhh;
  const float *d_wih, *d_whh, *d_bih, *d_bhh;
  const float *lin_w, *lin_b, *tp_w, *tp_b;
  u16 *Wenc, *Wencp, *Wdec, *wihP, *linT, *tpw;
  float *bias_e, *bias_ep, *bias_d, *bias_part;
  u16 *xf, *zf;
  u16 *he, *hp;            // 11 step-buffers each
  u16 *hs;                 // 25 decoder h buffers
  u16 *atth;               // 25 step-buffers
  float *c_pub;            // 2 ping-pong f32 [256][1024]
  unsigned *bar;           // 768 slots x 64B: [0,256) full, [256,512) enc, [512,768) lane
  float *out;
};

DEV float b2f(u16 v) { unsigned u = ((unsigned)v) << 16; float f; __builtin_memcpy(&f, &u, 4); return f; }
DEV u16 f2b(float f) {
  unsigned u; __builtin_memcpy(&u, &f, 4);
  unsigned r = u + 0x7fffu + ((u >> 16) & 1u);   // RNE
  return (u16)(r >> 16);
}
DEV unsigned pk2(float a, float b) { return (unsigned)f2b(a) | ((unsigned)f2b(b) << 16); }
DEV uint4 cvt8(const float* s) {
  float4 a = *(const float4*)s;
  float4 b = *(const float4*)(s + 4);
  uint4 r;
  r.x = pk2(a.x, a.y); r.y = pk2(a.z, a.w);
  r.z = pk2(b.x, b.y); r.w = pk2(b.z, b.w);
  return r;
}
DEV float sigm(float x) { return 1.0f / (1.0f + __expf(-x)); }
DEV f32x4_t fzero4() { f32x4_t v = {0.f, 0.f, 0.f, 0.f}; return v; }

DEV void gll16(const void* g, void* l) {
  __builtin_amdgcn_global_load_lds(
      (const __attribute__((address_space(1))) void*)g,
      (__attribute__((address_space(3))) void*)l, 16, 0, 0);
}

template <typename T> DEV void st_wt(T* p, T v) {
  __hip_atomic_store(p, v, __ATOMIC_RELAXED, __HIP_MEMORY_SCOPE_AGENT);
}
template <typename T> DEV T ld_byp(const T* p) {
  return __hip_atomic_load(p, __ATOMIC_RELAXED, __HIP_MEMORY_SCOPE_AGENT);
}

// ---- store-based barrier: one slot per block (no atomic RMW contention).
// Arrival = single st_wt of the epoch; wait = parallel per-thread polls.
DEV void sbar(unsigned* slots, int base, int idx, int n, unsigned ep, int tid) {
  asm volatile("s_waitcnt vmcnt(0)" ::: "memory");   // prior stores complete
  __syncthreads();
  if (tid == 0) st_wt(&slots[(base + idx) * 16], ep);
  for (int i = tid; i < n; i += NTHR)
    while (ld_byp(&slots[(base + i) * 16]) < ep) __builtin_amdgcn_s_sleep(2);
  __syncthreads();
}

// ------------- 64m x 128n tile bf16 GEMM, 8 waves of 32x32 (encoders) ------
// LDS: lA = sm[0..32K) 4 slots x 8KB; lB = sm[32K..96K) 4 slots x 16KB.
// slot(ks) = (ks+2)&3. Source-side XOR swizzle + same XOR on ds_read_b128.
// PM: 0 = stage A+B slots 0,1 at entry; 1 = caller prestaged A+B slots 0,1
// (prestaged data already DRAINED to LDS by a prior barrier's vmcnt(0)).
template <int PM>
DEV void gemm128(const u16* __restrict__ xa, int ldx, int xcols,
                 const u16* __restrict__ ha, int ldh,
                 const u16* __restrict__ wsrc, int ldw, int K,
                 int m0, int n0, int tid, char* sm, f32x4_t acc[4]) {
  char* lA = sm;
  char* lB = sm + 32768;
  const int NK = K >> 6;
  const int row = tid >> 3;
  const int usw = ((tid & 7) ^ (row & 7)) * 8;
  const int wv = tid >> 6;
  char* laD = lA + (wv << 10);
  char* lbD = lB + (wv << 10);
  const u16* aX = xa + (size_t)(m0 + row) * ldx + usw;
  const u16* aH = ha + (size_t)(m0 + row) * ldh + usw - xcols;
  const u16* bW0 = wsrc + (size_t)(n0 + row) * ldw + usw;
  const u16* bW1 = bW0 + (size_t)64 * ldw;

  auto sA = [&](int ks) {
    const int k0 = ks << 6;
    const u16* g = (k0 < xcols) ? (aX + k0) : (aH + k0);
    gll16(g, laD + (((ks + 2) & 3) << 13));
  };
  auto sB = [&](int ks) {
    const int k0 = ks << 6;
    const int so = ((ks + 2) & 3) << 14;
    gll16(bW0 + k0, lbD + so);
    gll16(bW1 + k0, lbD + so + 8192);
  };

  const int l = tid & 63, l15 = l & 15, lhi = l >> 4;
  const int wr = wv >> 2, wc = wv & 3;   // 2m x 4n wave grid, 32x32 wave tile
  const int rA0 = wr * 32 + l15, rA1 = rA0 + 16;
  const int nB0 = wc * 32 + l15, nB1 = nB0 + 16;
  const int a00 = rA0 * 128 + ((lhi ^ (rA0 & 7)) << 4);
  const int a01 = rA0 * 128 + (((lhi + 4) ^ (rA0 & 7)) << 4);
  const int a10 = rA1 * 128 + ((lhi ^ (rA1 & 7)) << 4);
  const int a11 = rA1 * 128 + (((lhi + 4) ^ (rA1 & 7)) << 4);
  const int b00 = nB0 * 128 + ((lhi ^ (nB0 & 7)) << 4);
  const int b01 = nB0 * 128 + (((lhi + 4) ^ (nB0 & 7)) << 4);
  const int b10 = nB1 * 128 + ((lhi ^ (nB1 & 7)) << 4);
  const int b11 = nB1 * 128 + (((lhi + 4) ^ (nB1 & 7)) << 4);

  if (PM == 0) { sA(0); sB(0); sA(1); sB(1); }

#pragma unroll 1
  for (int ks = 0; ks < NK; ++ks) {
    if (ks + 2 < NK) { sA(ks + 2); sB(ks + 2); }
    if (ks + 2 < NK)        asm volatile("s_waitcnt vmcnt(6)" ::: "memory");
    else if (ks + 2 == NK)  asm volatile("s_waitcnt vmcnt(3)" ::: "memory");
    else                    asm volatile("s_waitcnt vmcnt(0)" ::: "memory");
    __builtin_amdgcn_s_barrier();
    const char* A  = lA + (((ks + 2) & 3) << 13);
    const char* Bq = lB + (((ks + 2) & 3) << 14);
#pragma unroll
    for (int kh = 0; kh < 2; ++kh) {
      bf16x8_t va0 = *(const bf16x8_t*)(A + (kh ? a01 : a00));
      bf16x8_t va1 = *(const bf16x8_t*)(A + (kh ? a11 : a10));
      bf16x8_t vb0 = *(const bf16x8_t*)(Bq + (kh ? b01 : b00));
      bf16x8_t vb1 = *(const bf16x8_t*)(Bq + (kh ? b11 : b10));
      acc[0] = __builtin_amdgcn_mfma_f32_16x16x32_bf16(va0, vb0, acc[0], 0, 0, 0);
      acc[1] = __builtin_amdgcn_mfma_f32_16x16x32_bf16(va0, vb1, acc[1], 0, 0, 0);
      acc[2] = __builtin_amdgcn_mfma_f32_16x16x32_bf16(va1, vb0, acc[2], 0, 0, 0);
      acc[3] = __builtin_amdgcn_mfma_f32_16x16x32_bf16(va1, vb1, acc[3], 0, 0, 0);
    }
  }
  asm volatile("s_waitcnt lgkmcnt(0)" ::: "memory");
  __builtin_amdgcn_s_barrier();
}

// Prestage helpers for gemm128 (must match its addressing/slot map exactly)
DEV void preA128(const u16* src, int lds_, int m0, int tid, char* sm, int ks) {
  const int row = tid >> 3, usw = ((tid & 7) ^ (row & 7)) * 8, wv = tid >> 6;
  gll16(src + (size_t)(m0 + row) * lds_ + (ks << 6) + usw,
        sm + (wv << 10) + (((ks + 2) & 3) << 13));
}
DEV void preB128(const u16* w, int ldw, int n0, int tid, char* sm, int ks) {
  const int row = tid >> 3, usw = ((tid & 7) ^ (row & 7)) * 8, wv = tid >> 6;
  char* d = sm + 32768 + (wv << 10) + (((ks + 2) & 3) << 14);
  gll16(w + (size_t)(n0 + row) * ldw + (ks << 6) + usw, d);
  gll16(w + (size_t)(n0 + 64 + row) * ldw + (ks << 6) + usw, d + 8192);
}

// ------------- 64x64-tile bf16 GEMM (decoder) -------------------------------
// LDS: lB = sm[0..32K) 4 slots x 8K; lA = sm[32K..64K) 4 slots x 8K.
// slot(ks) = ks&3. PRE=0: B slots 0,1 prestaged+drained, A staged at entry.
// PRE=1: A and B slots 0,1 both prestaged+drained (entry issues nothing).
template <int PRE>
DEV void gemm64d(const u16* __restrict__ a, int lda,
                 const u16* __restrict__ w, int ldw, int K,
                 int m0, int n0, int tid, char* sm, f32x4_t acc[2]) {
  char* lB = sm;
  char* lA = sm + 32768;
  const int NK = K >> 6;
  const int row = tid >> 3, uu = tid & 7;
  const int usw = uu ^ (row & 7);
  const int wv = tid >> 6;
  char* la_base = lA + (wv << 10);
  char* lb_base = lB + (wv << 10);
  const u16* aS = a + (size_t)(m0 + row) * lda + usw * 8;
  const u16* bS = w + (size_t)(n0 + row) * ldw + usw * 8;

  auto stageA = [&](int ks) { gll16(aS + (ks << 6), la_base + ((ks & 3) << 13)); };
  auto stage  = [&](int ks) {
    gll16(aS + (ks << 6), la_base + ((ks & 3) << 13));
    gll16(bS + (ks << 6), lb_base + ((ks & 3) << 13));
  };

  const int l = tid & 63, l15 = l & 15, lhi = l >> 4;
  const int wr = wv >> 1, wc = wv & 1;       // 4x2 wave grid, wave tile 16x32
  const int rA = wr * 16 + l15;
  const int aoff0 = rA * 128 + ((lhi ^ (rA & 7)) << 4);
  const int aoff1 = rA * 128 + (((lhi + 4) ^ (rA & 7)) << 4);
  const int nB0 = wc * 32 + l15, nB1 = nB0 + 16;
  const int boff00 = nB0 * 128 + ((lhi ^ (nB0 & 7)) << 4);
  const int boff01 = nB0 * 128 + (((lhi + 4) ^ (nB0 & 7)) << 4);
  const int boff10 = nB1 * 128 + ((lhi ^ (nB1 & 7)) << 4);
  const int boff11 = nB1 * 128 + (((lhi + 4) ^ (nB1 & 7)) << 4);

  if (PRE == 0) { stageA(0); stageA(1); }

#pragma unroll 1
  for (int ks = 0; ks < NK; ++ks) {
    if (ks + 2 < NK) stage(ks + 2);
    if (ks == 0) {
      if (PRE == 0) asm volatile("s_waitcnt vmcnt(3)" ::: "memory");
      else          asm volatile("s_waitcnt vmcnt(2)" ::: "memory");
    }
    else if (ks + 2 < NK)   asm volatile("s_waitcnt vmcnt(4)" ::: "memory");
    else if (ks + 2 == NK)  asm volatile("s_waitcnt vmcnt(2)" ::: "memory");
    else                    asm volatile("s_waitcnt vmcnt(0)" ::: "memory");
    __builtin_amdgcn_s_barrier();
    const char* A  = lA + ((ks & 3) << 13);
    const char* Bb = lB + ((ks & 3) << 13);
    bf16x8_t a0  = *(const bf16x8_t*)(A + aoff0);
    bf16x8_t a1  = *(const bf16x8_t*)(A + aoff1);
    bf16x8_t b00 = *(const bf16x8_t*)(Bb + boff00);
    bf16x8_t b01 = *(const bf16x8_t*)(Bb + boff01);
    bf16x8_t b10 = *(const bf16x8_t*)(Bb + boff10);
    bf16x8_t b11 = *(const bf16x8_t*)(Bb + boff11);
    acc[0] = __builtin_amdgcn_mfma_f32_16x16x32_bf16(a0, b00, acc[0], 0, 0, 0);
    acc[0] = __builtin_amdgcn_mfma_f32_16x16x32_bf16(a1, b01, acc[0], 0, 0, 0);
    acc[1] = __builtin_amdgcn_mfma_f32_16x16x32_bf16(a0, b10, acc[1], 0, 0, 0);
    acc[1] = __builtin_amdgcn_mfma_f32_16x16x32_bf16(a1, b11, acc[1], 0, 0, 0);
  }
  asm volatile("s_waitcnt lgkmcnt(0)" ::: "memory");
  __builtin_amdgcn_s_barrier();
}

// Prestage for gemm64d (exact addressing match)
DEV void preB64(const u16* w, int ldw, int n0, int tid, char* sm, int ks) {
  const int row = tid >> 3, usw = (tid & 7) ^ (row & 7), wv = tid >> 6;
  gll16(w + (size_t)(n0 + row) * ldw + (ks << 6) + usw * 8,
        sm + (wv << 10) + ((ks & 3) << 13));
}
DEV void preA64(const u16* a, int lda, int m0, int tid, char* sm, int ks) {
  const int row = tid >> 3, usw = (tid & 7) ^ (row & 7), wv = tid >> 6;
  gll16(a + (size_t)(m0 + row) * lda + (ks << 6) + usw * 8,
        sm + 32768 + (wv << 10) + ((ks & 3) << 13));
}

// --------- LSTM epilogue, enc variant: [64][128] f32 overlay @ sm[0..32K) ---
DEV void lstm_ep128(const f32x4_t acc[4], int tid, char* sm,
                    const float* __restrict__ bias, float cc[4],
                    u16* __restrict__ hw, float* __restrict__ cpub,
                    int m0, int n0) {
  float* gl = (float*)sm;
  const int l = tid & 63, l15 = l & 15, lhi = l >> 4;
  const int wv = tid >> 6, wr = wv >> 2, wc = wv & 3;
#pragma unroll
  for (int mf = 0; mf < 2; ++mf)
#pragma unroll
    for (int nf = 0; nf < 2; ++nf)
#pragma unroll
      for (int qq = 0; qq < 4; ++qq)
        gl[(wr * 32 + mf * 16 + lhi * 4 + qq) * 128 + wc * 32 + nf * 16 + l15] =
            acc[mf * 2 + nf][qq];
  __syncthreads();
#pragma unroll
  for (int it = 0; it < 4; ++it) {
    int idx = it * 512 + tid;            // 2048 items: 64 rows x 32 j
    int r = idx >> 5, jj = idx & 31;
    f32x4_t g4 = *(const f32x4_t*)(gl + r * 128 + jj * 4);
    f32x4_t b4 = *(const f32x4_t*)(bias + n0 + jj * 4);
    float ig = sigm(g4[0] + b4[0]);
    float fg = sigm(g4[1] + b4[1]);
    float g_ = tanhf(g4[2] + b4[2]);
    float og = sigm(g4[3] + b4[3]);
    float cn = fg * cc[it] + ig * g_;
    cc[it] = cn;
    float hn = og * tanhf(cn);
    size_t off = (size_t)(m0 + r) * 1024 + (n0 >> 2) + jj;
    st_wt(&hw[off], f2b(hn));
    if (cpub) st_wt(&cpub[off], cn);
  }
  __syncthreads();
}

// --------- LSTM epilogue, dec variant: [64][64] f32 overlay @ sm+65536 ------
DEV void lstm_ep64(const f32x4_t acc[2], int tid, char* sm,
                   const float* __restrict__ bias, float cc[2],
                   const float* __restrict__ cinit,
                   u16* __restrict__ hw, float* __restrict__ cpub,
                   int m0, int n0) {
  float* gl = (float*)(sm + 65536);
  const int l = tid & 63, l15 = l & 15, lhi = l >> 4;
  const int wv = tid >> 6, wr = wv >> 1, wc = wv & 1;
#pragma unroll
  for (int jf = 0; jf < 2; ++jf)
#pragma unroll
    for (int qq = 0; qq < 4; ++qq)
      gl[(wr * 16 + lhi * 4 + qq) * 64 + wc * 32 + jf * 16 + l15] = acc[jf][qq];
  __syncthreads();
#pragma unroll
  for (int it = 0; it < 2; ++it) {
    int idx = it * 512 + tid;           // 1024 items: 64 rows x 16 j
    int r = idx >> 4, jj = idx & 15;
    f32x4_t g4 = *(const f32x4_t*)(gl + r * 64 + jj * 4);
    f32x4_t b4 = *(const f32x4_t*)(bias + n0 + jj * 4);
    float ig = sigm(g4[0] + b4[0]);
    float fg = sigm(g4[1] + b4[1]);
    float g_ = tanhf(g4[2] + b4[2]);
    float og = sigm(g4[3] + b4[3]);
    size_t off = (size_t)(m0 + r) * 1024 + (n0 >> 2) + jj;
    float cold = cinit ? ld_byp(cinit + off) : cc[it];
    float cn = fg * cold + ig * g_;
    cc[it] = cn;
    float hn = og * tanhf(cn);
    st_wt(&hw[off], f2b(hn));
    if (cpub) st_wt(&cpub[off], cn);
  }
  __syncthreads();
}

DEV void wx_store(const f32x4_t acc[4], int tid, u16* __restrict__ Wdec,
                  int m0, int n0) {
  const int l = tid & 63, l15 = l & 15, lhi = l >> 4;
  const int wv = tid >> 6, wr = wv >> 2, wc = wv & 3;
#pragma unroll
  for (int mf = 0; mf < 2; ++mf)
#pragma unroll
    for (int nf = 0; nf < 2; ++nf)
#pragma unroll
      for (int qq = 0; qq < 4; ++qq) {
        int r = m0 + wr * 32 + mf * 16 + lhi * 4 + qq;
        int c = n0 + wc * 32 + nf * 16 + l15;
        st_wt(&Wdec[(size_t)r * 2048 + c], f2b(acc[mf * 2 + nf][qq]));
      }
}

// ------------------- phase 0: ToFeature (block-cooperative) ----------------
DEV void phase0_tf(const Params& p, int bid, int tid, char* sm) {
  float* xs = (float*)sm;            // [10][66]
  float* zs = (float*)(sm + 2688);
  for (int g = tid; g < 660; g += NTHR) {
    int t = g / 66, qd = g - t * 66;
    xs[g] = p.x[((size_t)bid * 10 + t) * 66 + qd];
    zs[g] = p.z[((size_t)bid * 10 + t) * 66 + qd];
  }
  __syncthreads();
  const int n = tid;
  float accx[10], accz[10];
  float bn = p.tf_b[n];
#pragma unroll
  for (int t = 0; t < 10; ++t) { accx[t] = bn; accz[t] = bn; }
  const float* wrow = p.tf_w + (size_t)n * 66;
  for (int k = 0; k < 66; ++k) {
    float wk = wrow[k];
#pragma unroll
    for (int t = 0; t < 10; ++t) {
      accx[t] = fmaf(wk, xs[t * 66 + k], accx[t]);
      accz[t] = fmaf(wk, zs[t * 66 + k], accz[t]);
    }
  }
#pragma unroll
  for (int t = 0; t < 10; ++t) {
    p.xf[(size_t)t * 131072 + (size_t)bid * 512 + n] = f2b(accx[t]);
    p.zf[(size_t)t * 131072 + (size_t)bid * 512 + n] = f2b(accz[t]);
  }
  __syncthreads();
}

// --------------------------- phase 0a: conversions -------------------------
DEV void phase0a(const Params& p, int gtid) {
  for (int g = gtid; g < 786432; g += NT_ALL) {     // enc/encp 4096 x 192 units
    int row = g / 192;
    int u = g - row * 192;
    int k = u * 8;
    int nsrc = (row & 3) * 1024 + (row >> 2);       // gate-interleaved rows
    const float* s1 = (k < 512) ? (p.e_wih + (size_t)nsrc * 512 + k)
                                : (p.e_whh + (size_t)nsrc * 1024 + (k - 512));
    ((uint4*)p.Wenc)[g] = cvt8(s1);
    const float* s2 = (k < 512) ? (p.p_wih + (size_t)nsrc * 512 + k)
                                : (p.p_whh + (size_t)nsrc * 1024 + (k - 512));
    ((uint4*)p.Wencp)[g] = cvt8(s2);
  }
  for (int g = gtid; g < 524288; g += NT_ALL) {     // dec whh -> Wdec[:,1024:]
    int row = g >> 7, u = g & 127;
    int nsrc = (row & 3) * 1024 + (row >> 2);
    ((uint4*)p.Wdec)[row * 256 + 128 + u] = cvt8(p.d_whh + (size_t)nsrc * 1024 + u * 8);
  }
  for (int g = gtid; g < 262144; g += NT_ALL) {     // dec wih (gate-permuted)
    int row = g >> 6, u = g & 63;
    int nsrc = (row & 3) * 1024 + (row >> 2);
    ((uint4*)p.wihP)[g] = cvt8(p.d_wih + (size_t)nsrc * 512 + u * 8);
  }
  for (int g = gtid; g < 524288; g += NT_ALL) {     // lin_w transpose
    int f = g >> 10, h = g & 1023;
    p.linT[(size_t)h * 512 + f] = f2b(p.lin_w[g]);
  }
  for (int g = gtid; g < 8448; g += NT_ALL)
    ((uint4*)p.tpw)[g] = cvt8(p.tp_w + g * 8);
  for (int g = gtid; g < 4096; g += NT_ALL) {       // enc biases
    int nsrc = (g & 3) * 1024 + (g >> 2);
    p.bias_e[g]  = p.e_bih[nsrc] + p.e_bhh[nsrc];
    p.bias_ep[g] = p.p_bih[nsrc] + p.p_bhh[nsrc];
  }
  for (int g = gtid; g < 32768; g += NT_ALL) {      // bias_d partials (wih@lin_b)
    int cell = g >> 3, sub = g & 7;
    int nsrc = (cell & 3) * 1024 + (cell >> 2);
    const float* wr_ = p.d_wih + (size_t)nsrc * 512 + sub * 64;
    const float* lb = p.lin_b + sub * 64;
    float s = 0.f;
    for (int f = 0; f < 64; ++f) s += wr_[f] * lb[f];
    p.bias_part[g] = s;
  }
  uint4 zz; zz.x = zz.y = zz.z = zz.w = 0u;         // zero h0 for both encoders
  for (int g = gtid; g < 32768; g += NT_ALL) { ((uint4*)p.he)[g] = zz; ((uint4*)p.hp)[g] = zz; }
}

// --------------------- attention (persistent catl in LDS) ------------------
// catl loaded once before the decode loop; per step only slot 10 (hd row) and
// cl (c row) are refreshed. Touches only [96K+): gemm A/B slots survive.
DEV void attention2(const u16* hd_prev, const float* cpub, u16* atth_s,
                    int b, int tid, char* sm, bool refresh) {
  u16*   catl = (u16*)(sm + CATL_OFF);
  float* cl   = (float*)(sm + CL_OFF);
  float* sc   = (float*)(sm + SC_OFF);
  if (refresh) {
    for (int g = tid; g < 128; g += NTHR)
      ((uint4*)catl)[10 * 128 + g] = *(const uint4*)(hd_prev + (size_t)b * 1024 + g * 8);
  }
  for (int g = tid; g < 512; g += NTHR) {
    unsigned long long v = ld_byp(((const unsigned long long*)(cpub + (size_t)b * 1024)) + g);
    ((unsigned long long*)cl)[g] = v;
  }
  __syncthreads();   // also drains caller's prestaged gemm1 A/B slots
  const int wv = tid >> 6, l = tid & 63;
  for (int t = wv; t < 21; t += 8) {
    float s = 0.f;
    const u16* cr = catl + t * 1024;
    for (int hh = l; hh < 1024; hh += 64) s += cl[hh] * b2f(cr[hh]);
#pragma unroll
    for (int o = 32; o; o >>= 1) s += __shfl_down(s, o);
    if (l == 0) sc[t] = s;
  }
  __syncthreads();
  float m = -1e30f;
#pragma unroll
  for (int t = 0; t < 21; ++t) m = fmaxf(m, sc[t]);
  float e[21]; float den = 0.f;
#pragma unroll
  for (int t = 0; t < 21; ++t) { e[t] = __expf(sc[t] - m); den += e[t]; }
  float inv = 1.0f / den;
  const int h0 = tid * 2;
  float a0 = 0.f, a1 = 0.f;
#pragma unroll
  for (int t = 0; t < 21; ++t) {
    float w_ = e[t] * inv;
    unsigned v = *(const unsigned*)(catl + t * 1024 + h0);
    a0 += w_ * b2f((u16)(v & 0xffff));
    a1 += w_ * b2f((u16)(v >> 16));
  }
  st_wt(((unsigned*)(atth_s + (size_t)b * 1024)) + tid, pk2(a0, a1));
  // no trailing sync: catl/cl/sc regions are disjoint from all gemm regions
}

// ------------------------- final projection (1 b / block) ------------------
DEV void finalproj(const Params& p, int b, int tid, char* sm) {
  u16* hl = (u16*)sm;                     // [25][1024] bf16 = 51200 B
  for (int g = tid; g < 3200; g += NTHR) {
    int t = g >> 7, hu = g & 127;
    ((uint4*)hl)[g] = *(const uint4*)(p.hs + ((size_t)(t * 256 + b)) * 1024 + hu * 8);
  }
  __syncthreads();
  if (tid < 330) {
    int pcol = tid % 66, tg = tid / 66;
    float acc[5] = {0.f, 0.f, 0.f, 0.f, 0.f};
    const u16* wrow = p.tpw + (size_t)pcol * 1024;
    for (int hc = 0; hc < 128; ++hc) {
      uint4 wv4 = ((const uint4*)wrow)[hc];
      float wf[8];
      wf[0] = b2f(wv4.x & 0xffff); wf[1] = b2f(wv4.x >> 16);
      wf[2] = b2f(wv4.y & 0xffff); wf[3] = b2f(wv4.y >> 16);
      wf[4] = b2f(wv4.z & 0xffff); wf[5] = b2f(wv4.z >> 16);
      wf[6] = b2f(wv4.w & 0xffff); wf[7] = b2f(wv4.w >> 16);
#pragma unroll
      for (int r = 0; r < 5; ++r) {
        int t = tg * 5 + r;
        uint4 hv = ((const uint4*)(hl + t * 1024))[hc];
        float s;
        s  = wf[0] * b2f(hv.x & 0xffff) + wf[1] * b2f(hv.x >> 16);
        s += wf[2] * b2f(hv.y & 0xffff) + wf[3] * b2f(hv.y >> 16);
        s += wf[4] * b2f(hv.z & 0xffff) + wf[5] * b2f(hv.z >> 16);
        s += wf[6] * b2f(hv.w & 0xffff) + wf[7] * b2f(hv.w >> 16);
        acc[r] += s;
      }
    }
    float bb = p.tp_b[pcol];
#pragma unroll
    for (int r = 0; r < 5; ++r) {
      int t = tg * 5 + r;
      size_t o = (size_t)b * 1650 + (size_t)t * 66 + pcol;
      p.out[o] = acc[r] + bb + p.resid[o];
    }
  }
}

// ------------------------------- main kernel -------------------------------
__global__ __launch_bounds__(NTHR) void model_kernel(Params p) {
  cg::grid_group gg = cg::this_grid();
  extern __shared__ __align__(16) char sm[];
  const int tid = threadIdx.x;
  const int bid = blockIdx.x;
  const int gtid = bid * NTHR + tid;

  phase0_tf(p, bid, tid, sm);
  phase0a(p, gtid);
  if (bid == 0)
    for (int g = tid; g < 768; g += NTHR) st_wt(&p.bar[g * 16], 0u);
  gg.sync();                      // ONLY full-fence sync (flushes phase0 writes)

  // finalize bias_d
  for (int g = gtid; g < 4096; g += NT_ALL) {
    int nsrc = (g & 3) * 1024 + (g >> 2);
    float s = p.d_bih[nsrc] + p.d_bhh[nsrc];
#pragma unroll
    for (int k8 = 0; k8 < 8; ++k8) s += p.bias_part[g * 8 + k8];
    st_wt(&p.bias_d[g], s);
  }

  // P0b: Wdec[:,0:1024] = (gate-permuted dec_wih) @ lin_w  (lin fused)
#pragma unroll 1
  for (int i = 0; i < 2; ++i) {
    int tt = bid * 2 + i;
    int m0w = (tt & 63) << 6;
    int n0w = (tt >> 6) << 7;
    f32x4_t acc[4] = {fzero4(), fzero4(), fzero4(), fzero4()};
    gemm128<0>(p.wihP, 512, 512, p.wihP, 512, p.linT, 512, 512,
               m0w, n0w, tid, sm, acc);
    wx_store(acc, tid, p.Wdec, m0w, n0w);
  }

  // Encoder geometry (grid halves): grp0 = enc(x), grp1 = encp(z)
  const int grp = bid >> 7;
  const int q = bid & 127;
  const int m0e = (q >> 5) << 6;
  const int n0e = (q & 31) << 7;

  // Decoder geometry (4 lanes x 64 n-tiles; j&7 pins XCD weight slice)
  const int lane = bid >> 6, j = bid & 63;
  const int m0d = lane << 6;
  const int n0d = ((j & 7) * 8 + (j >> 3)) << 6;

  const u16* xsrc = grp ? p.zf : p.xf;
  const u16* Wg   = grp ? p.Wencp : p.Wenc;
  u16* hbuf       = grp ? p.hp : p.he;
  const float* bias_g = grp ? p.bias_ep : p.bias_e;

  // prestage encoder t=0 (xf/zf + W static), then the post-setup full barrier
  preA128(xsrc, 512, m0e, tid, sm, 0);
  preB128(Wg, 1536, n0e, tid, sm, 0);
  preA128(xsrc, 512, m0e, tid, sm, 1);
  preB128(Wg, 1536, n0e, tid, sm, 1);
  sbar(p.bar, 0, bid, 256, 1u, tid);

  float cc[4] = {0.f, 0.f, 0.f, 0.f};

  // P1: encoders on independent halves (128-block store-barriers)
#pragma unroll 1
  for (int t = 0; t < 10; ++t) {
    f32x4_t acc[4] = {fzero4(), fzero4(), fzero4(), fzero4()};
    gemm128<1>(xsrc + (size_t)t * 131072, 512, 512, hbuf + (size_t)t * HSTRIDE, 1024,
               Wg, 1536, 1536, m0e, n0e, tid, sm, acc);
    lstm_ep128(acc, tid, sm, bias_g, cc, hbuf + (size_t)(t + 1) * HSTRIDE,
               (!grp && t == 9) ? p.c_pub : (float*)0, m0e, n0e);
    if (t < 9) {
      preA128(xsrc + (size_t)(t + 1) * 131072, 512, m0e, tid, sm, 0);
      preB128(Wg, 1536, n0e, tid, sm, 0);
      preA128(xsrc + (size_t)(t + 1) * 131072, 512, m0e, tid, sm, 1);
      preB128(Wg, 1536, n0e, tid, sm, 1);
    } else {
      preB64(p.Wdec, 2048, n0d, tid, sm, 0);    // decode gemm1 B panel
      preB64(p.Wdec, 2048, n0d, tid, sm, 1);
    }
    sbar(p.bar, 256 + grp * 128, q, 128, (unsigned)(t + 1), tid);
  }
  sbar(p.bar, 0, bid, 256, 2u, tid);

  // load persistent catl: he[1..10], he[10] (initial hd), hp[1..10]
  {
    u16* catl = (u16*)(sm + CATL_OFF);
    for (int g = tid; g < 2688; g += NTHR) {
      int t = g >> 7, hu = g & 127;
      const u16* src;
      if (t < 10)       src = p.he + (size_t)(t + 1) * HSTRIDE;
      else if (t == 10) src = p.he + (size_t)10 * HSTRIDE;
      else              src = p.hp + (size_t)(t - 10) * HSTRIDE;
      ((uint4*)catl)[g] = *(const uint4*)(src + (size_t)bid * 1024 + hu * 8);
    }
  }

  // P3: decoder. preA(gemm1) -> att (drains it) -> gemm1(pre-drained) ->
  // preB(gemm2) -> BAR_A -> gemm2 -> ep -> preB(gemm1') -> BAR_B.
  float cd[2] = {0.f, 0.f};
  unsigned lep = 0;
#pragma unroll 1
  for (int s = 0; s < 25; ++s) {
    const u16* hd_prev = (s == 0) ? (p.he + (size_t)10 * HSTRIDE)
                                  : (p.hs + (size_t)(s - 1) * HSTRIDE);
    u16* atth_s = p.atth + (size_t)s * HSTRIDE;
    preA64(hd_prev, 1024, m0d, tid, sm, 0);
    preA64(hd_prev, 1024, m0d, tid, sm, 1);
    attention2(hd_prev, p.c_pub + (size_t)(s & 1) * 262144, atth_s, bid, tid, sm, s > 0);
    f32x4_t acc[2]; acc[0] = fzero4(); acc[1] = fzero4();
    gemm64d<1>(hd_prev, 1024, p.Wdec, 2048, 1024, m0d, n0d, tid, sm, acc);
    preB64(p.Wdec + 1024, 2048, n0d, tid, sm, 0);   // gemm2 B panel
    preB64(p.Wdec + 1024, 2048, n0d, tid, sm, 1);
    ++lep; sbar(p.bar, 512 + lane * 64, j, 64, lep, tid);   // atth ready
    gemm64d<0>(atth_s, 1024, p.Wdec + 1024, 2048, 1024, m0d, n0d, tid, sm, acc);
    lstm_ep64(acc, tid, sm, p.bias_d, cd,
              (s == 0) ? p.c_pub : (const float*)0,
              p.hs + (size_t)s * HSTRIDE,
              p.c_pub + (size_t)((s + 1) & 1) * 262144, m0d, n0d);
    if (s < 24) {
      preB64(p.Wdec, 2048, n0d, tid, sm, 0);        // next step gemm1 B panel
      preB64(p.Wdec, 2048, n0d, tid, sm, 1);
    }
    ++lep; sbar(p.bar, 512 + lane * 64, j, 64, lep, tid);   // hs[s], c_pub ready
  }

  // P4: out = dec_h @ tp_w.T + tp_b + for_resid
  finalproj(p, bid, tid, sm);
}

// ------------------------------- host launch -------------------------------
extern "C" void kernel_launch(void* const* d_in, const int* in_sizes, int n_in,
                              void* d_out, int out_size, void* d_ws, size_t ws_size,
                              hipStream_t stream) {
  (void)in_sizes; (void)n_in; (void)out_size;
  Params P;
  P.x     = (const float*)d_in[0];
  P.z     = (const float*)d_in[1];
  P.resid = (const float*)d_in[2];
  P.tf_w  = (const float*)d_in[3];
  P.tf_b  = (const float*)d_in[4];
  P.e_wih = (const float*)d_in[5];
  P.e_whh = (const float*)d_in[6];
  P.e_bih = (const float*)d_in[7];
  P.e_bhh = (const float*)d_in[8];
  P.p_wih = (const float*)d_in[9];
  P.p_whh = (const float*)d_in[10];
  P.p_bih = (const float*)d_in[11];
  P.p_bhh = (const float*)d_in[12];
  P.d_wih = (const float*)d_in[13];
  P.d_whh = (const float*)d_in[14];
  P.d_bih = (const float*)d_in[15];
  P.d_bhh = (const float*)d_in[16];
  P.lin_w = (const float*)d_in[17];
  P.lin_b = (const float*)d_in[18];
  P.tp_w  = (const float*)d_in[19];
  P.tp_b  = (const float*)d_in[20];

  char* w = (char*)d_ws;
  size_t o = 0;
  auto take = [&](size_t bytes) { char* r = w + o; o = (o + bytes + 255) & ~(size_t)255; return r; };
  P.Wenc  = (u16*)take(4096ull * 1536 * 2);
  P.Wencp = (u16*)take(4096ull * 1536 * 2);
  P.Wdec  = (u16*)take(4096ull * 2048 * 2);
  P.wihP  = (u16*)take(4096ull * 512 * 2);
  P.linT  = (u16*)take(1024ull * 512 * 2);
  P.tpw   = (u16*)take(66ull * 1024 * 2);
  P.bias_e    = (float*)take(4096 * 4);
  P.bias_ep   = (float*)take(4096 * 4);
  P.bias_d    = (float*)take(4096 * 4);
  P.bias_part = (float*)take(32768 * 4);
  P.xf  = (u16*)take(10ull * 256 * 512 * 2);
  P.zf  = (u16*)take(10ull * 256 * 512 * 2);
  P.he  = (u16*)take(11ull * 256 * 1024 * 2);
  P.hp  = (u16*)take(11ull * 256 * 1024 * 2);
  P.hs  = (u16*)take(25ull * 256 * 1024 * 2);
  P.atth = (u16*)take(25ull * 256 * 1024 * 2);
  P.c_pub = (float*)take(2ull * 256 * 1024 * 4);
  P.bar   = (unsigned*)take(768 * 64);
  P.out = (float*)d_out;

  if (o > ws_size) return;  // workspace too small: fail cleanly, no corruption

  hipFuncSetAttribute((const void*)model_kernel,
                      hipFuncAttributeMaxDynamicSharedMemorySize, SMEM_BYTES);

  void* args[] = { &P };
  hipLaunchCooperativeKernel((const void*)model_kernel, dim3(NBLK, 1, 1),
                             dim3(NTHR, 1, 1), args, SMEM_BYTES, stream);
}